// Round 4
// baseline (1854.121 us; speedup 1.0000x reference)
//
#include <hip/hip_runtime.h>
#include <hip/hip_bf16.h>

#define NN   16384
#define EE   65536
#define GG   64
#define INF  63
#define HID  2048
#define MID  1024
#define NCLS 18
#define EPS  1e-5f
#define SLOPE 0.01f

typedef unsigned short ushort;
typedef unsigned int uint;

using bf16x8 = __attribute__((ext_vector_type(8))) __bf16;
using f32x4  = __attribute__((ext_vector_type(4))) float;

__device__ __forceinline__ ushort f2us(float x) {
    __hip_bfloat16 b = __float2bfloat16(x);
    return __builtin_bit_cast(ushort, b);
}
__device__ __forceinline__ float us2f(ushort u) {
    return __bfloat162float(__builtin_bit_cast(__hip_bfloat16, u));
}

// async global->LDS, 16B per lane; LDS base wave-uniform, HW adds lane*16
__device__ __forceinline__ void gll16(const ushort* g, ushort* l) {
    __builtin_amdgcn_global_load_lds(
        (const __attribute__((address_space(1))) uint*)g,
        (__attribute__((address_space(3))) uint*)l, 16, 0, 0);
}

// ---------------- utility ----------------

__global__ void k_zero_i(int* __restrict__ p, int n) {
    int i = blockIdx.x * blockDim.x + threadIdx.x;
    if (i < n) p[i] = 0;
}

// ---------------- CSR build (by dst) ----------------

__global__ void k_count(const int* __restrict__ dst, int* __restrict__ cnt) {
    int e = blockIdx.x * blockDim.x + threadIdx.x;
    if (e < EE) atomicAdd(&cnt[dst[e]], 1);
}

__global__ void k_scan(const int* __restrict__ cnt, int* __restrict__ off,
                       float* __restrict__ deg) {
    __shared__ int sh[1024];
    int t = threadIdx.x;
    int base = t * 16;
    int loc[16];
    int s = 0;
#pragma unroll
    for (int i = 0; i < 16; ++i) {
        int c = cnt[base + i];
        loc[i] = s;
        s += c;
        deg[base + i] = (float)c;
    }
    sh[t] = s;
    __syncthreads();
    for (int d = 1; d < 1024; d <<= 1) {
        int v = (t >= d) ? sh[t - d] : 0;
        __syncthreads();
        sh[t] += v;
        __syncthreads();
    }
    int excl = sh[t] - s;
#pragma unroll
    for (int i = 0; i < 16; ++i) off[base + i] = excl + loc[i];
    if (t == 1023) off[NN] = sh[1023];
}

__global__ void k_fill(const int* __restrict__ src, const int* __restrict__ dst,
                       const int* __restrict__ off, int* __restrict__ cur,
                       int* __restrict__ csr_src) {
    int e = blockIdx.x * blockDim.x + threadIdx.x;
    if (e < EE) {
        int d = dst[e];
        int p = atomicAdd(&cur[d], 1);
        csr_src[off[d] + p] = src[e];
    }
}

// ---------------- aggregation ----------------

// layer 1: nmbf[v][f] = mean_h over neighbors, 64-wide zero-padded bf16
__global__ void k_agg_small(const float* __restrict__ X, ushort* __restrict__ nmbf,
                            const int* __restrict__ off, const int* __restrict__ csr_src,
                            const float* __restrict__ deg) {
    int v = blockIdx.x;
    int f = threadIdx.x;  // 64
    float acc = 0.f;
    if (f < INF) {
        int s = off[v], e = off[v + 1];
        for (int i = s; i < e; ++i) acc += X[(size_t)csr_src[i] * INF + f];
        acc /= fmaxf(deg[v], 1.f);
    }
    nmbf[(size_t)v * 64 + f] = f2us(acc);
}

// h fp32 [NN,63] -> bf16 [NN,64] zero-padded
__global__ void k_h2bf(const float* __restrict__ h, ushort* __restrict__ hbf) {
    int i = blockIdx.x * 256 + threadIdx.x;
    int r = i >> 6, c = i & 63;
    hbf[i] = (c < INF) ? f2us(h[(size_t)r * INF + c]) : (ushort)0;
}

// wide: AggX[v][:] = mean over neighbors of X rows (bf16 in/out, fp32 accum)
// block per node, 256 threads x 8 cols (uint4 = 8 bf16)
__global__ void k_aggX(const ushort* __restrict__ X, ushort* __restrict__ A,
                       const int* __restrict__ off, const int* __restrict__ csr_src,
                       const float* __restrict__ deg) {
    int v = blockIdx.x;
    int t = threadIdx.x;
    int s = off[v], e = off[v + 1];
    float acc[8];
#pragma unroll
    for (int j = 0; j < 8; ++j) acc[j] = 0.f;
    for (int i = s; i < e; ++i) {
        const uint4* p = (const uint4*)(X + (size_t)csr_src[i] * HID) + t;
        uint4 u = *p;
        uint w[4] = {u.x, u.y, u.z, u.w};
#pragma unroll
        for (int j = 0; j < 4; ++j) {
            acc[2 * j]     += us2f((ushort)(w[j] & 0xffffu));
            acc[2 * j + 1] += us2f((ushort)(w[j] >> 16));
        }
    }
    float inv = 1.f / fmaxf(deg[v], 1.f);
    uint o[4];
#pragma unroll
    for (int j = 0; j < 4; ++j)
        o[j] = (uint)f2us(acc[2 * j] * inv) | ((uint)f2us(acc[2 * j + 1] * inv) << 16);
    ((uint4*)(A + (size_t)v * HID))[t] = make_uint4(o[0], o[1], o[2], o[3]);
}

// ---------------- weight transpose + bf16: Wt[n][k]=bf16(W[k][n]), k<Kp pad0

__global__ void k_wt(const float* __restrict__ W, int K, int N,
                     ushort* __restrict__ Wt, int Kp) {
    __shared__ float t[32][33];
    int kb = blockIdx.y * 32, nb = blockIdx.x * 32;
    int tx = threadIdx.x & 31, ty = threadIdx.x >> 5;
#pragma unroll
    for (int i = 0; i < 32; i += 8) {
        int k = kb + ty + i;
        t[ty + i][tx] = (k < K) ? W[(size_t)k * N + nb + tx] : 0.f;
    }
    __syncthreads();
#pragma unroll
    for (int i = 0; i < 32; i += 8)
        Wt[(size_t)(nb + ty + i) * Kp + kb + tx] = f2us(t[tx][ty + i]);
}

// ---------------- MFMA GEMM (m97 structure, two-pass) ----------------------
// C = A1@B1t^T + A2@B2t^T + bias[local col]; A bf16 [M,K] lda, Bt bf16 [N,K] ldb
// 128x128 tile, BK=32, 256 thr (4 waves), wave = 64x64 quadrant of 4x4 mfma.

#define BK 32

__global__ __launch_bounds__(256)
void k_mgemm(const ushort* __restrict__ A1, int lda1, const ushort* __restrict__ B1t, int ldb1, int K1,
             const ushort* __restrict__ A2, int lda2, const ushort* __restrict__ B2t, int ldb2, int K2,
             const float* __restrict__ bias, float* __restrict__ Cf, ushort* __restrict__ Cbf,
             int ldc, int fuse_lrelu) {
    __shared__ __align__(16) ushort As[128 * BK];
    __shared__ __align__(16) ushort Bs[128 * BK];
    const int tid = threadIdx.x;
    const int lane = tid & 63;
    const int w = tid >> 6;
    const int rowBase = blockIdx.y * 128;
    const int colBase = blockIdx.x * 128;
    const int m0 = (w & 1) * 64;
    const int n0 = (w >> 1) * 64;

    f32x4 acc[4][4];
#pragma unroll
    for (int mi = 0; mi < 4; ++mi)
#pragma unroll
        for (int ni = 0; ni < 4; ++ni) acc[mi][ni] = (f32x4){0.f, 0.f, 0.f, 0.f};

    const int i0 = w * 128 + lane;
    const int i1 = i0 + 64;
    const int r0i = i0 >> 2, c0i = i0 & 3;
    const int r1i = i1 >> 2, c1i = i1 & 3;
    ushort* ldsA0 = As + w * 1024;
    ushort* ldsA1 = As + w * 1024 + 512;
    ushort* ldsB0 = Bs + w * 1024;
    ushort* ldsB1 = Bs + w * 1024 + 512;
    const int la = lane & 15, q = lane >> 4;

    for (int pass = 0; pass < 2; ++pass) {
        const ushort* A  = pass ? A2 : A1;
        const ushort* Bt = pass ? B2t : B1t;
        const int K   = pass ? K2 : K1;
        const int lda = pass ? lda2 : lda1;
        const int ldb = pass ? ldb2 : ldb1;
        if (A == nullptr) continue;
        const ushort* gA0 = A + (size_t)(rowBase + r0i) * lda + c0i * 8;
        const ushort* gA1 = A + (size_t)(rowBase + r1i) * lda + c1i * 8;
        const ushort* gB0 = Bt + (size_t)(colBase + r0i) * ldb + c0i * 8;
        const ushort* gB1 = Bt + (size_t)(colBase + r1i) * ldb + c1i * 8;
        for (int kt = 0; kt < K; kt += BK) {
            gll16(gA0 + kt, ldsA0);
            gll16(gA1 + kt, ldsA1);
            gll16(gB0 + kt, ldsB0);
            gll16(gB1 + kt, ldsB1);
            __syncthreads();
            bf16x8 av[4], bv[4];
#pragma unroll
            for (int mi = 0; mi < 4; ++mi)
                av[mi] = *(const bf16x8*)&As[(m0 + mi * 16 + la) * BK + q * 8];
#pragma unroll
            for (int ni = 0; ni < 4; ++ni)
                bv[ni] = *(const bf16x8*)&Bs[(n0 + ni * 16 + la) * BK + q * 8];
#pragma unroll
            for (int mi = 0; mi < 4; ++mi)
#pragma unroll
                for (int ni = 0; ni < 4; ++ni)
                    acc[mi][ni] = __builtin_amdgcn_mfma_f32_16x16x32_bf16(
                        av[mi], bv[ni], acc[mi][ni], 0, 0, 0);
            __syncthreads();
        }
    }

    // epilogue: C/D layout col = lane&15, row = q*4 + reg
#pragma unroll
    for (int mi = 0; mi < 4; ++mi) {
#pragma unroll
        for (int ni = 0; ni < 4; ++ni) {
            const int lc = colBase + n0 + ni * 16 + la;  // local col in this GEMM's N range
            const float bv = bias ? bias[lc] : 0.f;
#pragma unroll
            for (int r = 0; r < 4; ++r) {
                const int row = rowBase + m0 + mi * 16 + q * 4 + r;
                float v = acc[mi][ni][r] + bv;
                if (fuse_lrelu) v = v > 0.f ? v : SLOPE * v;
                if (Cbf) Cbf[(size_t)row * ldc + lc] = f2us(v);
                else     Cf[(size_t)row * ldc + lc] = v;
            }
        }
    }
}

// ---------------- BatchNorm (deterministic two-stage, column-chunkable) ----

__global__ void k_bn_stats(const float* __restrict__ Y, int CW,
                           float* __restrict__ p1, float* __restrict__ p2) {
    int col = blockIdx.x * 256 + threadIdx.x;
    int rb = blockIdx.y;
    int r0 = rb * 256;
    float a = 0.f, b = 0.f;
    for (int r = 0; r < 256; ++r) {
        float v = Y[(size_t)(r0 + r) * CW + col];
        a += v;
        b += v * v;
    }
    p1[(size_t)rb * CW + col] = a;
    p2[(size_t)rb * CW + col] = b;
}

__global__ void k_bn_finalize(const float* __restrict__ p1, const float* __restrict__ p2,
                              const float* __restrict__ gamma, const float* __restrict__ beta,
                              float* __restrict__ scale, float* __restrict__ shift, int CW) {
    int c = blockIdx.x * 256 + threadIdx.x;
    if (c >= CW) return;
    float s1 = 0.f, s2 = 0.f;
    for (int rb = 0; rb < 64; ++rb) {
        s1 += p1[(size_t)rb * CW + c];
        s2 += p2[(size_t)rb * CW + c];
    }
    float mean = s1 * (1.f / (float)NN);
    float var = s2 * (1.f / (float)NN) - mean * mean;
    var = fmaxf(var, 0.f);
    float sc = gamma[c] * rsqrtf(var + EPS);
    scale[c] = sc;
    shift[c] = beta[c] - mean * sc;
}

struct alignas(8) us4 { ushort u[4]; };

// Xout[row][c0 + lc] = bf16(lrelu(scale*Y[row][lc] + shift)), Y is [NN,CW]
__global__ void k_bn_apply(const float* __restrict__ Y, int CW4,
                           const float* __restrict__ scale, const float* __restrict__ shift,
                           ushort* __restrict__ Xout, int c0) {
    int i4 = blockIdx.x * 256 + threadIdx.x;
    int row = i4 / CW4;
    int lc4 = (i4 - row * CW4) * 4;
    float4 x = ((const float4*)Y)[i4];
    float4 sc = *(const float4*)&scale[lc4];
    float4 sh = *(const float4*)&shift[lc4];
    float4 y;
    y.x = sc.x * x.x + sh.x;
    y.y = sc.y * x.y + sh.y;
    y.z = sc.z * x.z + sh.z;
    y.w = sc.w * x.w + sh.w;
    y.x = y.x > 0.f ? y.x : SLOPE * y.x;
    y.y = y.y > 0.f ? y.y : SLOPE * y.y;
    y.z = y.z > 0.f ? y.z : SLOPE * y.z;
    y.w = y.w > 0.f ? y.w : SLOPE * y.w;
    us4 pk = {{f2us(y.x), f2us(y.y), f2us(y.z), f2us(y.w)}};
    *(us4*)(Xout + (size_t)row * HID + c0 + lc4) = pk;
}

// ---------------- pooling + head ----------------

__global__ void k_gstart(const int* __restrict__ gid, int* __restrict__ gstart) {
    int g = threadIdx.x;
    if (g > GG) return;
    int lo = 0, hi = NN;
    while (lo < hi) {
        int mid = (lo + hi) >> 1;
        if (gid[mid] < g) lo = mid + 1; else hi = mid;
    }
    gstart[g] = lo;
}

// X bf16 [NN,HID] -> hg fp32 [GG,HID]
__global__ void k_pool(const ushort* __restrict__ X, const int* __restrict__ gstart,
                       float* __restrict__ hg) {
    int g = blockIdx.y;
    int col = blockIdx.x * 256 + threadIdx.x;
    int s = gstart[g], e = gstart[g + 1];
    float acc = 0.f;
    for (int n = s; n < e; ++n) acc += us2f(X[(size_t)n * HID + col]);
    hg[(size_t)g * HID + col] = acc / fmaxf((float)(e - s), 1.f);
}

__global__ void k_hg2bf(const float* __restrict__ hg, ushort* __restrict__ hgbf) {
    int i = blockIdx.x * 256 + threadIdx.x;  // over 128*HID
    int r = i >> 11;
    hgbf[i] = (r < GG) ? f2us(hg[i]) : (ushort)0;
}

__global__ void k_fc3(const float* __restrict__ x2, const float* __restrict__ W,
                      const float* __restrict__ b, float* __restrict__ out) {
    int g = blockIdx.x;
    int tid = threadIdx.x;
    float part[NCLS];
#pragma unroll
    for (int c = 0; c < NCLS; ++c) part[c] = 0.f;
    for (int k = tid; k < MID; k += 256) {
        float x = x2[(size_t)g * MID + k];
        const float* wr = W + (size_t)k * NCLS;
#pragma unroll
        for (int c = 0; c < NCLS; ++c) part[c] += x * wr[c];
    }
    __shared__ float red[4][NCLS];
    int lane = tid & 63, w = tid >> 6;
#pragma unroll
    for (int c = 0; c < NCLS; ++c) {
        float v = part[c];
        for (int o = 32; o > 0; o >>= 1) v += __shfl_down(v, o, 64);
        if (lane == 0) red[w][c] = v;
    }
    __syncthreads();
    if (tid < NCLS)
        out[(size_t)g * NCLS + tid] = red[0][tid] + red[1][tid] + red[2][tid] + red[3][tid] + b[tid];
}

// ---------------- launcher ----------------

extern "C" void kernel_launch(void* const* d_in, const int* in_sizes, int n_in,
                              void* d_out, int out_size, void* d_ws, size_t ws_size,
                              hipStream_t stream) {
    const float* h        = (const float*)d_in[0];
    const int*   src      = (const int*)d_in[1];
    const int*   dst      = (const int*)d_in[2];
    const int*   graph_id = (const int*)d_in[3];
    const float* Ws1 = (const float*)d_in[4];
    const float* Wn1 = (const float*)d_in[5];
    const float* b1  = (const float*)d_in[6];
    const float* Ws2 = (const float*)d_in[7];
    const float* Wn2 = (const float*)d_in[8];
    const float* b2  = (const float*)d_in[9];
    const float* Ws3 = (const float*)d_in[10];
    const float* Wn3 = (const float*)d_in[11];
    const float* b3  = (const float*)d_in[12];
    const float* g1  = (const float*)d_in[13];
    const float* be1 = (const float*)d_in[14];
    const float* g2  = (const float*)d_in[15];
    const float* be2 = (const float*)d_in[16];
    const float* g3  = (const float*)d_in[17];
    const float* be3 = (const float*)d_in[18];
    const float* fc1_w = (const float*)d_in[19];
    const float* fc1_b = (const float*)d_in[20];
    const float* fc2_w = (const float*)d_in[21];
    const float* fc2_b = (const float*)d_in[22];
    const float* fc3_w = (const float*)d_in[23];
    const float* fc3_b = (const float*)d_in[24];
    float* out = (float*)d_out;

    size_t off_b = 0;
    auto alloc = [&](size_t bytes) -> void* {
        void* p = (char*)d_ws + off_b;
        off_b += (bytes + 255) & ~(size_t)255;
        return p;
    };
    ushort* Wt0    = (ushort*)alloc((size_t)2 * HID * HID * 2);  // 16 MiB (2 slots)
    ushort* Wt1    = Wt0 + (size_t)HID * HID;
    ushort* X      = (ushort*)alloc((size_t)NN * HID * 2);       // 64 MiB
    ushort* AggX   = (ushort*)alloc((size_t)NN * HID * 2);       // 64 MiB (hosts hbf/nmbf in L1)
    float*  deg    = (float*)alloc((size_t)NN * 4);
    int*    csroff = (int*)alloc((size_t)(NN + 1) * 4);
    int*    cursor = (int*)alloc((size_t)NN * 4);
    int*    csrsrc = (int*)alloc((size_t)EE * 4);
    float*  p1     = (float*)alloc((size_t)64 * HID * 4);
    float*  p2     = (float*)alloc((size_t)64 * HID * 4);
    float*  bnsc   = (float*)alloc((size_t)HID * 4);
    float*  bnsh   = (float*)alloc((size_t)HID * 4);
    int*    gstart = (int*)alloc((size_t)(GG + 1) * 4);
    size_t fixed = off_b;

    // plan select (ws_size constant across calls -> deterministic)
    int CW;
    float*  Yc;
    ushort* X2;  // ping-pong partner (plan A: in-place)
    if (ws_size >= fixed + (size_t)NN * HID * 4 + 4096) {
        CW = 2048;                                   // plan A: full-width, BN after GEMM, in-place
        Yc = (float*)alloc((size_t)NN * HID * 4);    // 128 MiB
        X2 = X;
    } else if (ws_size >= fixed + (size_t)NN * HID * 2 + (size_t)NN * 512 * 4 + 4096) {
        CW = 512;                                    // plan B: column-chunked BN, ping-pong
        X2 = (ushort*)alloc((size_t)NN * HID * 2);
        Yc = (float*)alloc((size_t)NN * 512 * 4);
    } else {
        CW = 256;
        X2 = (ushort*)alloc((size_t)NN * HID * 2);
        Yc = (float*)alloc((size_t)NN * 256 * 4);
    }
    ushort* hbf  = AggX;                     // layer-1 A inputs live in AggX region
    ushort* nmbf = AggX + (size_t)NN * 64;
    // head buffers carved from Yc region (dead after layer 3)
    float*  hg   = (float*)Yc;
    ushort* hgbf = (ushort*)((char*)Yc + (1 << 20));
    ushort* x1bf = (ushort*)((char*)Yc + (2 << 20));
    float*  x2f  = (float*)((char*)Yc + (3 << 20));

    // ---- CSR build ----
    k_zero_i<<<dim3(NN / 256), dim3(256), 0, stream>>>(cursor, NN);
    k_count<<<dim3(EE / 256), dim3(256), 0, stream>>>(dst, cursor);
    k_scan<<<dim3(1), dim3(1024), 0, stream>>>(cursor, csroff, deg);
    k_zero_i<<<dim3(NN / 256), dim3(256), 0, stream>>>(cursor, NN);
    k_fill<<<dim3(EE / 256), dim3(256), 0, stream>>>(src, dst, csroff, cursor, csrsrc);

    const int CW4 = CW / 4;
    // one layer: transpose weights, then per column-chunk GEMM(K1+K2) -> BN -> Xout
    auto runLayer = [&](const ushort* A1, int lda1, int K1,
                        const ushort* A2, int lda2, int K2,
                        const float* Ws, const float* Wn, int Kw, int Kp,
                        const float* b, const float* gamma, const float* beta,
                        ushort* Xout) {
        k_wt<<<dim3(HID / 32, Kp / 32), dim3(256), 0, stream>>>(Ws, Kw, HID, Wt0, Kp);
        k_wt<<<dim3(HID / 32, Kp / 32), dim3(256), 0, stream>>>(Wn, Kw, HID, Wt1, Kp);
        for (int c0 = 0; c0 < HID; c0 += CW) {
            k_mgemm<<<dim3(CW / 128, NN / 128), dim3(256), 0, stream>>>(
                A1, lda1, Wt0 + (size_t)c0 * Kp, Kp, K1,
                A2, lda2, Wt1 + (size_t)c0 * Kp, Kp, K2,
                b + c0, Yc, (ushort*)nullptr, CW, 0);
            k_bn_stats<<<dim3(CW / 256, 64), dim3(256), 0, stream>>>(Yc, CW, p1, p2);
            k_bn_finalize<<<dim3((CW + 255) / 256), dim3(256), 0, stream>>>(
                p1, p2, gamma + c0, beta + c0, bnsc, bnsh, CW);
            k_bn_apply<<<dim3(NN * CW4 / 256), dim3(256), 0, stream>>>(
                Yc, CW4, bnsc, bnsh, Xout, c0);
        }
    };

    // ---- layer 1: K = 64 + 64 (padded from 63) ----
    k_h2bf<<<dim3(NN * 64 / 256), dim3(256), 0, stream>>>(h, hbf);
    k_agg_small<<<dim3(NN), dim3(64), 0, stream>>>(h, nmbf, csroff, csrsrc, deg);
    runLayer(hbf, 64, 64, nmbf, 64, 64, Ws1, Wn1, INF, 64, b1, g1, be1, X);

    // ---- layer 2: K = 2048 + 2048 merged ----
    k_aggX<<<dim3(NN), dim3(256), 0, stream>>>(X, AggX, csroff, csrsrc, deg);
    ushort* l2out = (CW == 2048) ? X : X2;
    runLayer(X, HID, HID, AggX, HID, HID, Ws2, Wn2, HID, HID, b2, g2, be2, l2out);

    // ---- layer 3 ----
    ushort* l3in = l2out;
    k_aggX<<<dim3(NN), dim3(256), 0, stream>>>(l3in, AggX, csroff, csrsrc, deg);
    runLayer(l3in, HID, HID, AggX, HID, HID, Ws3, Wn3, HID, HID, b3, g3, be3, X);

    // ---- pooling ----
    k_gstart<<<dim3(1), dim3(128), 0, stream>>>(graph_id, gstart);
    k_pool<<<dim3(HID / 256, GG), dim3(256), 0, stream>>>(X, gstart, hg);
    k_hg2bf<<<dim3(128 * HID / 256), dim3(256), 0, stream>>>(hg, hgbf);

    // ---- MLP head ----
    k_wt<<<dim3(HID / 32, HID / 32), dim3(256), 0, stream>>>(fc1_w, HID, HID, Wt0, HID);
    k_wt<<<dim3(MID / 32, HID / 32), dim3(256), 0, stream>>>(fc2_w, HID, MID, Wt1, HID);
    k_mgemm<<<dim3(HID / 128, 1), dim3(256), 0, stream>>>(
        hgbf, HID, Wt0, HID, HID,
        (const ushort*)nullptr, 0, (const ushort*)nullptr, 0, 0,
        fc1_b, (float*)nullptr, x1bf, HID, 1);
    k_mgemm<<<dim3(MID / 128, 1), dim3(256), 0, stream>>>(
        x1bf, HID, Wt1, HID, HID,
        (const ushort*)nullptr, 0, (const ushort*)nullptr, 0, 0,
        fc2_b, x2f, (ushort*)nullptr, MID, 1);
    k_fc3<<<dim3(GG), dim3(256), 0, stream>>>(x2f, fc3_w, fc3_b, out);
}

// Round 5
// 1345.303 us; speedup vs baseline: 1.3782x; 1.3782x over previous
//
#include <hip/hip_runtime.h>
#include <hip/hip_bf16.h>

#define NN   16384
#define EE   65536
#define GG   64
#define INF  63
#define HID  2048
#define MID  1024
#define NCLS 18
#define EPS  1e-5f
#define SLOPE 0.01f
#define MR   (NN / 128)   // 128 block-rows for BN partials

typedef unsigned short ushort;
typedef unsigned int uint;

using bf16x8 = __attribute__((ext_vector_type(8))) __bf16;
using f32x4  = __attribute__((ext_vector_type(4))) float;

__device__ __forceinline__ ushort f2us(float x) {
    __hip_bfloat16 b = __float2bfloat16(x);
    return __builtin_bit_cast(ushort, b);
}
__device__ __forceinline__ float us2f(ushort u) {
    return __bfloat162float(__builtin_bit_cast(__hip_bfloat16, u));
}

// async global->LDS, 16B per lane; LDS base wave-uniform, HW adds lane*16
__device__ __forceinline__ void gll16(const ushort* g, ushort* l) {
    __builtin_amdgcn_global_load_lds(
        (const __attribute__((address_space(1))) uint*)g,
        (__attribute__((address_space(3))) uint*)l, 16, 0, 0);
}

// ---------------- utility ----------------

__global__ void k_zero_i(int* __restrict__ p, int n) {
    int i = blockIdx.x * blockDim.x + threadIdx.x;
    if (i < n) p[i] = 0;
}

// ---------------- CSR build (by dst) ----------------

__global__ void k_count(const int* __restrict__ dst, int* __restrict__ cnt) {
    int e = blockIdx.x * blockDim.x + threadIdx.x;
    if (e < EE) atomicAdd(&cnt[dst[e]], 1);
}

__global__ void k_scan(const int* __restrict__ cnt, int* __restrict__ off,
                       float* __restrict__ deg) {
    __shared__ int sh[1024];
    int t = threadIdx.x;
    int base = t * 16;
    int loc[16];
    int s = 0;
#pragma unroll
    for (int i = 0; i < 16; ++i) {
        int c = cnt[base + i];
        loc[i] = s;
        s += c;
        deg[base + i] = (float)c;
    }
    sh[t] = s;
    __syncthreads();
    for (int d = 1; d < 1024; d <<= 1) {
        int v = (t >= d) ? sh[t - d] : 0;
        __syncthreads();
        sh[t] += v;
        __syncthreads();
    }
    int excl = sh[t] - s;
#pragma unroll
    for (int i = 0; i < 16; ++i) off[base + i] = excl + loc[i];
    if (t == 1023) off[NN] = sh[1023];
}

__global__ void k_fill(const int* __restrict__ src, const int* __restrict__ dst,
                       const int* __restrict__ off, int* __restrict__ cur,
                       int* __restrict__ csr_src) {
    int e = blockIdx.x * blockDim.x + threadIdx.x;
    if (e < EE) {
        int d = dst[e];
        int p = atomicAdd(&cur[d], 1);
        csr_src[off[d] + p] = src[e];
    }
}

// ---------------- aggregation ----------------

__global__ void k_agg_small(const float* __restrict__ X, ushort* __restrict__ nmbf,
                            const int* __restrict__ off, const int* __restrict__ csr_src,
                            const float* __restrict__ deg) {
    int v = blockIdx.x;
    int f = threadIdx.x;  // 64
    float acc = 0.f;
    if (f < INF) {
        int s = off[v], e = off[v + 1];
        for (int i = s; i < e; ++i) acc += X[(size_t)csr_src[i] * INF + f];
        acc /= fmaxf(deg[v], 1.f);
    }
    nmbf[(size_t)v * 64 + f] = f2us(acc);
}

__global__ void k_h2bf(const float* __restrict__ h, ushort* __restrict__ hbf) {
    int i = blockIdx.x * 256 + threadIdx.x;
    int r = i >> 6, c = i & 63;
    hbf[i] = (c < INF) ? f2us(h[(size_t)r * INF + c]) : (ushort)0;
}

// AggX[v][:] = mean over neighbors of X rows (bf16 in/out, fp32 accum)
__global__ void k_aggX(const ushort* __restrict__ X, ushort* __restrict__ A,
                       const int* __restrict__ off, const int* __restrict__ csr_src,
                       const float* __restrict__ deg) {
    int v = blockIdx.x;
    int t = threadIdx.x;
    int s = off[v], e = off[v + 1];
    float acc[8];
#pragma unroll
    for (int j = 0; j < 8; ++j) acc[j] = 0.f;
    for (int i = s; i < e; ++i) {
        const uint4* p = (const uint4*)(X + (size_t)csr_src[i] * HID) + t;
        uint4 u = *p;
        uint w[4] = {u.x, u.y, u.z, u.w};
#pragma unroll
        for (int j = 0; j < 4; ++j) {
            acc[2 * j]     += us2f((ushort)(w[j] & 0xffffu));
            acc[2 * j + 1] += us2f((ushort)(w[j] >> 16));
        }
    }
    float inv = 1.f / fmaxf(deg[v], 1.f);
    uint o[4];
#pragma unroll
    for (int j = 0; j < 4; ++j)
        o[j] = (uint)f2us(acc[2 * j] * inv) | ((uint)f2us(acc[2 * j + 1] * inv) << 16);
    ((uint4*)(A + (size_t)v * HID))[t] = make_uint4(o[0], o[1], o[2], o[3]);
}

// ---------------- weight transpose + bf16: Wt[n][k]=bf16(W[k][n]) ----------

__global__ void k_wt(const float* __restrict__ W, int K, int N,
                     ushort* __restrict__ Wt, int Kp) {
    __shared__ float t[32][33];
    int kb = blockIdx.y * 32, nb = blockIdx.x * 32;
    int tx = threadIdx.x & 31, ty = threadIdx.x >> 5;
#pragma unroll
    for (int i = 0; i < 32; i += 8) {
        int k = kb + ty + i;
        t[ty + i][tx] = (k < K) ? W[(size_t)k * N + nb + tx] : 0.f;
    }
    __syncthreads();
#pragma unroll
    for (int i = 0; i < 32; i += 8)
        Wt[(size_t)(nb + ty + i) * Kp + kb + tx] = f2us(t[tx][ty + i]);
}

// ---------------- MFMA GEMM (m97 structure, two-pass, fused BN partials) ---
// C = A1@B1t^T + A2@B2t^T + bias; A bf16 [M,K] lda, Bt bf16 [N,K] ldb.
// 128x128 tile, BK=32, 256 thr (4 waves), wave = 64x64 quadrant of 4x4 mfma.
// If s1p: write per-block-row per-column partial sums/sumsq of (acc+bias)
// (pre-activation, fp32 exact) to s1p/s2p[blockIdx.y * ldc + col]. One writer
// per slot -> deterministic.

#define BK 32

__global__ __launch_bounds__(256)
void k_mgemm(const ushort* __restrict__ A1, int lda1, const ushort* __restrict__ B1t, int ldb1, int K1,
             const ushort* __restrict__ A2, int lda2, const ushort* __restrict__ B2t, int ldb2, int K2,
             const float* __restrict__ bias, float* __restrict__ Cf, ushort* __restrict__ Cbf,
             int ldc, int fuse_lrelu, float* __restrict__ s1p, float* __restrict__ s2p) {
    __shared__ __align__(16) ushort As[128 * BK];
    __shared__ __align__(16) ushort Bs[128 * BK];
    __shared__ float sb1[4][64];
    __shared__ float sb2[4][64];
    const int tid = threadIdx.x;
    const int lane = tid & 63;
    const int w = tid >> 6;
    const int rowBase = blockIdx.y * 128;
    const int colBase = blockIdx.x * 128;
    const int m0 = (w & 1) * 64;
    const int n0 = (w >> 1) * 64;

    f32x4 acc[4][4];
#pragma unroll
    for (int mi = 0; mi < 4; ++mi)
#pragma unroll
        for (int ni = 0; ni < 4; ++ni) acc[mi][ni] = (f32x4){0.f, 0.f, 0.f, 0.f};

    const int i0 = w * 128 + lane;
    const int i1 = i0 + 64;
    const int r0i = i0 >> 2, c0i = i0 & 3;
    const int r1i = i1 >> 2, c1i = i1 & 3;
    ushort* ldsA0 = As + w * 1024;
    ushort* ldsA1 = As + w * 1024 + 512;
    ushort* ldsB0 = Bs + w * 1024;
    ushort* ldsB1 = Bs + w * 1024 + 512;
    const int la = lane & 15, q = lane >> 4;

    for (int pass = 0; pass < 2; ++pass) {
        const ushort* A  = pass ? A2 : A1;
        const ushort* Bt = pass ? B2t : B1t;
        const int K   = pass ? K2 : K1;
        const int lda = pass ? lda2 : lda1;
        const int ldb = pass ? ldb2 : ldb1;
        if (A == nullptr) continue;
        const ushort* gA0 = A + (size_t)(rowBase + r0i) * lda + c0i * 8;
        const ushort* gA1 = A + (size_t)(rowBase + r1i) * lda + c1i * 8;
        const ushort* gB0 = Bt + (size_t)(colBase + r0i) * ldb + c0i * 8;
        const ushort* gB1 = Bt + (size_t)(colBase + r1i) * ldb + c1i * 8;
        for (int kt = 0; kt < K; kt += BK) {
            gll16(gA0 + kt, ldsA0);
            gll16(gA1 + kt, ldsA1);
            gll16(gB0 + kt, ldsB0);
            gll16(gB1 + kt, ldsB1);
            __syncthreads();
            bf16x8 av[4], bv[4];
#pragma unroll
            for (int mi = 0; mi < 4; ++mi)
                av[mi] = *(const bf16x8*)&As[(m0 + mi * 16 + la) * BK + q * 8];
#pragma unroll
            for (int ni = 0; ni < 4; ++ni)
                bv[ni] = *(const bf16x8*)&Bs[(n0 + ni * 16 + la) * BK + q * 8];
#pragma unroll
            for (int mi = 0; mi < 4; ++mi)
#pragma unroll
                for (int ni = 0; ni < 4; ++ni)
                    acc[mi][ni] = __builtin_amdgcn_mfma_f32_16x16x32_bf16(
                        av[mi], bv[ni], acc[mi][ni], 0, 0, 0);
            __syncthreads();
        }
    }

    // ---- C store (C/D layout: col = lane&15, row = q*4 + reg) ----
#pragma unroll
    for (int mi = 0; mi < 4; ++mi) {
#pragma unroll
        for (int ni = 0; ni < 4; ++ni) {
            const int lc = colBase + n0 + ni * 16 + la;
            const float bv = bias ? bias[lc] : 0.f;
#pragma unroll
            for (int r = 0; r < 4; ++r) {
                const int row = rowBase + m0 + mi * 16 + q * 4 + r;
                float v = acc[mi][ni][r] + bv;
                if (fuse_lrelu) v = v > 0.f ? v : SLOPE * v;
                if (Cbf) Cbf[(size_t)row * ldc + lc] = f2us(v);
                else     Cf[(size_t)row * ldc + lc] = v;
            }
        }
    }

    // ---- fused BN partial stats (pre-activation, fp32 exact) ----
    if (s1p) {
#pragma unroll
        for (int ni = 0; ni < 4; ++ni) {
            const int lc = colBase + n0 + ni * 16 + la;
            const float bv = bias ? bias[lc] : 0.f;
            float t1 = 0.f, t2 = 0.f;
#pragma unroll
            for (int mi = 0; mi < 4; ++mi)
#pragma unroll
                for (int r = 0; r < 4; ++r) {
                    float v = acc[mi][ni][r] + bv;
                    t1 += v;
                    t2 += v * v;
                }
            // reduce across q (lanes sharing la): rows m0..m0+63 covered
            t1 += __shfl_xor(t1, 16);
            t1 += __shfl_xor(t1, 32);
            t2 += __shfl_xor(t2, 16);
            t2 += __shfl_xor(t2, 32);
            if (q == 0) {
                sb1[w][ni * 16 + la] = t1;
                sb2[w][ni * 16 + la] = t2;
            }
        }
        __syncthreads();
        // waves 0,1 cover cols 0..63; waves 2,3 cover cols 64..127
        if (tid < 128) {
            int half = tid >> 6, j = tid & 63;
            float v1 = sb1[2 * half][j] + sb1[2 * half + 1][j];
            float v2 = sb2[2 * half][j] + sb2[2 * half + 1][j];
            size_t o = (size_t)blockIdx.y * ldc + colBase + half * 64 + j;
            s1p[o] = v1;
            s2p[o] = v2;
        }
    }
}

// ---------------- BatchNorm finalize + apply ----------------

__global__ void k_bn_finalize(const float* __restrict__ p1, const float* __restrict__ p2,
                              const float* __restrict__ gamma, const float* __restrict__ beta,
                              float* __restrict__ scale, float* __restrict__ shift) {
    int c = blockIdx.x * 256 + threadIdx.x;
    if (c >= HID) return;
    float s1 = 0.f, s2 = 0.f;
    for (int rb = 0; rb < MR; ++rb) {
        s1 += p1[(size_t)rb * HID + c];
        s2 += p2[(size_t)rb * HID + c];
    }
    float mean = s1 * (1.f / (float)NN);
    float var = s2 * (1.f / (float)NN) - mean * mean;
    var = fmaxf(var, 0.f);
    float sc = gamma[c] * rsqrtf(var + EPS);
    scale[c] = sc;
    shift[c] = beta[c] - mean * sc;
}

// X[i] = bf16(lrelu(scale*Y[i] + shift)), Y bf16, 8 elems/thread
__global__ void k_bn_apply8(const ushort* __restrict__ Y, const float* __restrict__ scale,
                            const float* __restrict__ shift, ushort* __restrict__ X) {
    int i8 = blockIdx.x * 256 + threadIdx.x;
    int c = (i8 * 8) & (HID - 1);
    uint4 u = ((const uint4*)Y)[i8];
    uint wds[4] = {u.x, u.y, u.z, u.w};
    uint o[4];
#pragma unroll
    for (int j = 0; j < 4; ++j) {
        float a = us2f((ushort)(wds[j] & 0xffffu));
        float b = us2f((ushort)(wds[j] >> 16));
        int cc = c + 2 * j;
        a = scale[cc] * a + shift[cc];
        b = scale[cc + 1] * b + shift[cc + 1];
        a = a > 0.f ? a : SLOPE * a;
        b = b > 0.f ? b : SLOPE * b;
        o[j] = (uint)f2us(a) | ((uint)f2us(b) << 16);
    }
    ((uint4*)X)[i8] = make_uint4(o[0], o[1], o[2], o[3]);
}

// ---------------- pooling + head ----------------

__global__ void k_gstart(const int* __restrict__ gid, int* __restrict__ gstart) {
    int g = threadIdx.x;
    if (g > GG) return;
    int lo = 0, hi = NN;
    while (lo < hi) {
        int mid = (lo + hi) >> 1;
        if (gid[mid] < g) lo = mid + 1; else hi = mid;
    }
    gstart[g] = lo;
}

__global__ void k_pool(const ushort* __restrict__ X, const int* __restrict__ gstart,
                       float* __restrict__ hg) {
    int g = blockIdx.y;
    int col = blockIdx.x * 256 + threadIdx.x;
    int s = gstart[g], e = gstart[g + 1];
    float acc = 0.f;
    for (int n = s; n < e; ++n) acc += us2f(X[(size_t)n * HID + col]);
    hg[(size_t)g * HID + col] = acc / fmaxf((float)(e - s), 1.f);
}

__global__ void k_hg2bf(const float* __restrict__ hg, ushort* __restrict__ hgbf) {
    int i = blockIdx.x * 256 + threadIdx.x;  // over 128*HID
    int r = i >> 11;
    hgbf[i] = (r < GG) ? f2us(hg[i]) : (ushort)0;
}

__global__ void k_fc3(const float* __restrict__ x2, const float* __restrict__ W,
                      const float* __restrict__ b, float* __restrict__ out) {
    int g = blockIdx.x;
    int tid = threadIdx.x;
    float part[NCLS];
#pragma unroll
    for (int c = 0; c < NCLS; ++c) part[c] = 0.f;
    for (int k = tid; k < MID; k += 256) {
        float x = x2[(size_t)g * MID + k];
        const float* wr = W + (size_t)k * NCLS;
#pragma unroll
        for (int c = 0; c < NCLS; ++c) part[c] += x * wr[c];
    }
    __shared__ float red[4][NCLS];
    int lane = tid & 63, w = tid >> 6;
#pragma unroll
    for (int c = 0; c < NCLS; ++c) {
        float v = part[c];
        for (int o = 32; o > 0; o >>= 1) v += __shfl_down(v, o, 64);
        if (lane == 0) red[w][c] = v;
    }
    __syncthreads();
    if (tid < NCLS)
        out[(size_t)g * NCLS + tid] = red[0][tid] + red[1][tid] + red[2][tid] + red[3][tid] + b[tid];
}

// ---------------- launcher ----------------

extern "C" void kernel_launch(void* const* d_in, const int* in_sizes, int n_in,
                              void* d_out, int out_size, void* d_ws, size_t ws_size,
                              hipStream_t stream) {
    const float* h        = (const float*)d_in[0];
    const int*   src      = (const int*)d_in[1];
    const int*   dst      = (const int*)d_in[2];
    const int*   graph_id = (const int*)d_in[3];
    const float* Ws1 = (const float*)d_in[4];
    const float* Wn1 = (const float*)d_in[5];
    const float* b1  = (const float*)d_in[6];
    const float* Ws2 = (const float*)d_in[7];
    const float* Wn2 = (const float*)d_in[8];
    const float* b2  = (const float*)d_in[9];
    const float* Ws3 = (const float*)d_in[10];
    const float* Wn3 = (const float*)d_in[11];
    const float* b3  = (const float*)d_in[12];
    const float* g1  = (const float*)d_in[13];
    const float* be1 = (const float*)d_in[14];
    const float* g2  = (const float*)d_in[15];
    const float* be2 = (const float*)d_in[16];
    const float* g3  = (const float*)d_in[17];
    const float* be3 = (const float*)d_in[18];
    const float* fc1_w = (const float*)d_in[19];
    const float* fc1_b = (const float*)d_in[20];
    const float* fc2_w = (const float*)d_in[21];
    const float* fc2_b = (const float*)d_in[22];
    const float* fc3_w = (const float*)d_in[23];
    const float* fc3_b = (const float*)d_in[24];
    float* out = (float*)d_out;

    size_t off_b = 0;
    auto alloc = [&](size_t bytes) -> void* {
        void* p = (char*)d_ws + off_b;
        off_b += (bytes + 255) & ~(size_t)255;
        return p;
    };
    ushort* Wt0    = (ushort*)alloc((size_t)2 * HID * HID * 2);  // 16 MiB (2 slots)
    ushort* Wt1    = Wt0 + (size_t)HID * HID;
    ushort* X      = (ushort*)alloc((size_t)NN * HID * 2);       // 64 MiB
    ushort* AggX   = (ushort*)alloc((size_t)NN * HID * 2);       // 64 MiB
    ushort* Ybf    = (ushort*)alloc((size_t)NN * HID * 2);       // 64 MiB
    float*  deg    = (float*)alloc((size_t)NN * 4);
    int*    csroff = (int*)alloc((size_t)(NN + 1) * 4);
    int*    cursor = (int*)alloc((size_t)NN * 4);
    int*    csrsrc = (int*)alloc((size_t)EE * 4);
    float*  p1     = (float*)alloc((size_t)MR * HID * 4);        // 1 MiB
    float*  p2     = (float*)alloc((size_t)MR * HID * 4);        // 1 MiB
    float*  bnsc   = (float*)alloc((size_t)HID * 4);
    float*  bnsh   = (float*)alloc((size_t)HID * 4);
    int*    gstart = (int*)alloc((size_t)(GG + 1) * 4);
    // total ~211 MiB (< the 245 MiB plan that ran in R4)

    ushort* hbf  = AggX;                       // layer-1 A inputs in AggX region
    ushort* nmbf = AggX + (size_t)NN * 64;
    // head buffers carved from Ybf (dead after final BN apply)
    float*  hg   = (float*)Ybf;
    ushort* hgbf = (ushort*)((char*)Ybf + (1 << 20));
    ushort* x1bf = (ushort*)((char*)Ybf + (2 << 20));
    float*  x2f  = (float*)((char*)Ybf + (3 << 20));

    // ---- CSR build ----
    k_zero_i<<<dim3(NN / 256), dim3(256), 0, stream>>>(cursor, NN);
    k_count<<<dim3(EE / 256), dim3(256), 0, stream>>>(dst, cursor);
    k_scan<<<dim3(1), dim3(1024), 0, stream>>>(cursor, csroff, deg);
    k_zero_i<<<dim3(NN / 256), dim3(256), 0, stream>>>(cursor, NN);
    k_fill<<<dim3(EE / 256), dim3(256), 0, stream>>>(src, dst, csroff, cursor, csrsrc);

    const int applyBlocks = NN * HID / 8 / 256;
    // one layer: GEMM(full width, fused stats, bf16 Y) -> finalize -> apply -> X
    auto runLayer = [&](const ushort* A1, int lda1, int K1,
                        const ushort* A2, int lda2, int K2,
                        const float* Ws, const float* Wn, int Kw, int Kp,
                        const float* b, const float* gamma, const float* beta) {
        k_wt<<<dim3(HID / 32, Kp / 32), dim3(256), 0, stream>>>(Ws, Kw, HID, Wt0, Kp);
        k_wt<<<dim3(HID / 32, Kp / 32), dim3(256), 0, stream>>>(Wn, Kw, HID, Wt1, Kp);
        k_mgemm<<<dim3(HID / 128, NN / 128), dim3(256), 0, stream>>>(
            A1, lda1, Wt0, Kp, K1,
            A2, lda2, Wt1, Kp, K2,
            b, (float*)nullptr, Ybf, HID, 0, p1, p2);
        k_bn_finalize<<<dim3(HID / 256), dim3(256), 0, stream>>>(p1, p2, gamma, beta, bnsc, bnsh);
        k_bn_apply8<<<dim3(applyBlocks), dim3(256), 0, stream>>>(Ybf, bnsc, bnsh, X);
    };

    // ---- layer 1: K = 64 + 64 (padded from 63) ----
    k_h2bf<<<dim3(NN * 64 / 256), dim3(256), 0, stream>>>(h, hbf);
    k_agg_small<<<dim3(NN), dim3(64), 0, stream>>>(h, nmbf, csroff, csrsrc, deg);
    runLayer(hbf, 64, 64, nmbf, 64, 64, Ws1, Wn1, INF, 64, b1, g1, be1);

    // ---- layer 2: K = 2048 + 2048 merged ----
    k_aggX<<<dim3(NN), dim3(256), 0, stream>>>(X, AggX, csroff, csrsrc, deg);
    runLayer(X, HID, HID, AggX, HID, HID, Ws2, Wn2, HID, HID, b2, g2, be2);

    // ---- layer 3 ----
    k_aggX<<<dim3(NN), dim3(256), 0, stream>>>(X, AggX, csroff, csrsrc, deg);
    runLayer(X, HID, HID, AggX, HID, HID, Ws3, Wn3, HID, HID, b3, g3, be3);

    // ---- pooling ----
    k_gstart<<<dim3(1), dim3(128), 0, stream>>>(graph_id, gstart);
    k_pool<<<dim3(HID / 256, GG), dim3(256), 0, stream>>>(X, gstart, hg);
    k_hg2bf<<<dim3(128 * HID / 256), dim3(256), 0, stream>>>(hg, hgbf);

    // ---- MLP head ----
    k_wt<<<dim3(HID / 32, HID / 32), dim3(256), 0, stream>>>(fc1_w, HID, HID, Wt0, HID);
    k_wt<<<dim3(MID / 32, HID / 32), dim3(256), 0, stream>>>(fc2_w, HID, MID, Wt1, HID);
    k_mgemm<<<dim3(HID / 128, 1), dim3(256), 0, stream>>>(
        hgbf, HID, Wt0, HID, HID,
        (const ushort*)nullptr, 0, (const ushort*)nullptr, 0, 0,
        fc1_b, (float*)nullptr, x1bf, HID, 1, (float*)nullptr, (float*)nullptr);
    k_mgemm<<<dim3(MID / 128, 1), dim3(256), 0, stream>>>(
        x1bf, HID, Wt1, HID, HID,
        (const ushort*)nullptr, 0, (const ushort*)nullptr, 0, 0,
        fc2_b, x2f, (ushort*)nullptr, MID, 1, (float*)nullptr, (float*)nullptr);
    k_fc3<<<dim3(GG), dim3(256), 0, stream>>>(x2f, fc3_w, fc3_b, out);
}

// Round 6
// 1325.209 us; speedup vs baseline: 1.3991x; 1.0152x over previous
//
#include <hip/hip_runtime.h>
#include <hip/hip_bf16.h>

#define NN   16384
#define EE   65536
#define GG   64
#define INF  63
#define HID  2048
#define MID  1024
#define NCLS 18
#define EPS  1e-5f
#define SLOPE 0.01f
#define MR   (NN / 128)   // 128 block-rows for BN partials

typedef unsigned short ushort;
typedef unsigned int uint;

using bf16x8 = __attribute__((ext_vector_type(8))) __bf16;
using f32x4  = __attribute__((ext_vector_type(4))) float;

__device__ __forceinline__ ushort f2us(float x) {
    __hip_bfloat16 b = __float2bfloat16(x);
    return __builtin_bit_cast(ushort, b);
}
__device__ __forceinline__ float us2f(ushort u) {
    return __bfloat162float(__builtin_bit_cast(__hip_bfloat16, u));
}

// async global->LDS, 16B per lane; LDS base wave-uniform, HW adds lane*16
__device__ __forceinline__ void gll16(const ushort* g, ushort* l) {
    __builtin_amdgcn_global_load_lds(
        (const __attribute__((address_space(1))) uint*)g,
        (__attribute__((address_space(3))) uint*)l, 16, 0, 0);
}

// ---------------- utility ----------------

__global__ void k_zero_i(int* __restrict__ p, int n) {
    int i = blockIdx.x * blockDim.x + threadIdx.x;
    if (i < n) p[i] = 0;
}

// ---------------- CSR build (by dst) ----------------

__global__ void k_count(const int* __restrict__ dst, int* __restrict__ cnt) {
    int e = blockIdx.x * blockDim.x + threadIdx.x;
    if (e < EE) atomicAdd(&cnt[dst[e]], 1);
}

__global__ void k_scan(const int* __restrict__ cnt, int* __restrict__ off,
                       float* __restrict__ deg) {
    __shared__ int sh[1024];
    int t = threadIdx.x;
    int base = t * 16;
    int loc[16];
    int s = 0;
#pragma unroll
    for (int i = 0; i < 16; ++i) {
        int c = cnt[base + i];
        loc[i] = s;
        s += c;
        deg[base + i] = (float)c;
    }
    sh[t] = s;
    __syncthreads();
    for (int d = 1; d < 1024; d <<= 1) {
        int v = (t >= d) ? sh[t - d] : 0;
        __syncthreads();
        sh[t] += v;
        __syncthreads();
    }
    int excl = sh[t] - s;
#pragma unroll
    for (int i = 0; i < 16; ++i) off[base + i] = excl + loc[i];
    if (t == 1023) off[NN] = sh[1023];
}

__global__ void k_fill(const int* __restrict__ src, const int* __restrict__ dst,
                       const int* __restrict__ off, int* __restrict__ cur,
                       int* __restrict__ csr_src) {
    int e = blockIdx.x * blockDim.x + threadIdx.x;
    if (e < EE) {
        int d = dst[e];
        int p = atomicAdd(&cur[d], 1);
        csr_src[off[d] + p] = src[e];
    }
}

// ---------------- layer-1 prep ----------------

__global__ void k_agg_small(const float* __restrict__ X, ushort* __restrict__ nmbf,
                            const int* __restrict__ off, const int* __restrict__ csr_src,
                            const float* __restrict__ deg) {
    int v = blockIdx.x;
    int f = threadIdx.x;  // 64
    float acc = 0.f;
    if (f < INF) {
        int s = off[v], e = off[v + 1];
        for (int i = s; i < e; ++i) acc += X[(size_t)csr_src[i] * INF + f];
        acc /= fmaxf(deg[v], 1.f);
    }
    nmbf[(size_t)v * 64 + f] = f2us(acc);
}

__global__ void k_h2bf(const float* __restrict__ h, ushort* __restrict__ hbf) {
    int i = blockIdx.x * 256 + threadIdx.x;
    int r = i >> 6, c = i & 63;
    hbf[i] = (c < INF) ? f2us(h[(size_t)r * INF + c]) : (ushort)0;
}

// ---------------- fused BN-apply + aggregation ----------------
// Reads pre-BN Ybf (bf16) + scale/shift; writes X[v] = bf16(lrelu(sc*y+sh))
// and AggX[v] = bf16(mean over neighbors of lrelu(sc*y+sh)) (fp32 accum).
// block = node v, 256 threads x 8 cols.

__global__ void k_aggbn(const ushort* __restrict__ Ybf,
                        const float* __restrict__ sc8, const float* __restrict__ sh8,
                        ushort* __restrict__ X, ushort* __restrict__ AggX,
                        const int* __restrict__ off, const int* __restrict__ csr_src,
                        const float* __restrict__ deg) {
    int v = blockIdx.x;
    int t = threadIdx.x;
    int c = t * 8;
    float sc[8], sh[8];
    *(float4*)&sc[0] = *(const float4*)&sc8[c];
    *(float4*)&sc[4] = *(const float4*)&sc8[c + 4];
    *(float4*)&sh[0] = *(const float4*)&sh8[c];
    *(float4*)&sh[4] = *(const float4*)&sh8[c + 4];

    // own row -> X
    {
        uint4 u = ((const uint4*)(Ybf + (size_t)v * HID))[t];
        uint wds[4] = {u.x, u.y, u.z, u.w};
        uint o[4];
#pragma unroll
        for (int j = 0; j < 4; ++j) {
            float a = sc[2 * j] * us2f((ushort)(wds[j] & 0xffffu)) + sh[2 * j];
            float b = sc[2 * j + 1] * us2f((ushort)(wds[j] >> 16)) + sh[2 * j + 1];
            a = a > 0.f ? a : SLOPE * a;
            b = b > 0.f ? b : SLOPE * b;
            o[j] = (uint)f2us(a) | ((uint)f2us(b) << 16);
        }
        ((uint4*)(X + (size_t)v * HID))[t] = make_uint4(o[0], o[1], o[2], o[3]);
    }

    // neighbor mean -> AggX
    int s = off[v], e = off[v + 1];
    float acc[8];
#pragma unroll
    for (int j = 0; j < 8; ++j) acc[j] = 0.f;
    for (int i = s; i < e; ++i) {
        uint4 u = ((const uint4*)(Ybf + (size_t)csr_src[i] * HID))[t];
        uint wds[4] = {u.x, u.y, u.z, u.w};
#pragma unroll
        for (int j = 0; j < 4; ++j) {
            float a = sc[2 * j] * us2f((ushort)(wds[j] & 0xffffu)) + sh[2 * j];
            float b = sc[2 * j + 1] * us2f((ushort)(wds[j] >> 16)) + sh[2 * j + 1];
            acc[2 * j]     += a > 0.f ? a : SLOPE * a;
            acc[2 * j + 1] += b > 0.f ? b : SLOPE * b;
        }
    }
    float inv = 1.f / fmaxf(deg[v], 1.f);
    uint o[4];
#pragma unroll
    for (int j = 0; j < 4; ++j)
        o[j] = (uint)f2us(acc[2 * j] * inv) | ((uint)f2us(acc[2 * j + 1] * inv) << 16);
    ((uint4*)(AggX + (size_t)v * HID))[t] = make_uint4(o[0], o[1], o[2], o[3]);
}

// ---------------- paired weight transpose + bf16 ----------------
// z=0: W0 -> Wt0 ; z=1: W1 -> Wt1.  Wt[n][k] = bf16(W[k][n]), k>=K pad 0.

__global__ void k_wt2(const float* __restrict__ W0, const float* __restrict__ W1,
                      int K, int N, ushort* __restrict__ Wt0, ushort* __restrict__ Wt1,
                      int Kp) {
    const float* W = blockIdx.z ? W1 : W0;
    ushort* Wt = blockIdx.z ? Wt1 : Wt0;
    __shared__ float t[32][33];
    int kb = blockIdx.y * 32, nb = blockIdx.x * 32;
    int tx = threadIdx.x & 31, ty = threadIdx.x >> 5;
#pragma unroll
    for (int i = 0; i < 32; i += 8) {
        int k = kb + ty + i;
        t[ty + i][tx] = (k < K) ? W[(size_t)k * N + nb + tx] : 0.f;
    }
    __syncthreads();
#pragma unroll
    for (int i = 0; i < 32; i += 8)
        Wt[(size_t)(nb + ty + i) * Kp + kb + tx] = f2us(t[tx][ty + i]);
}

// ---------------- MFMA GEMM (m97 structure, two-pass, fused BN partials) ---

#define BK 32

__global__ __launch_bounds__(256)
void k_mgemm(const ushort* __restrict__ A1, int lda1, const ushort* __restrict__ B1t, int ldb1, int K1,
             const ushort* __restrict__ A2, int lda2, const ushort* __restrict__ B2t, int ldb2, int K2,
             const float* __restrict__ bias, float* __restrict__ Cf, ushort* __restrict__ Cbf,
             int ldc, int fuse_lrelu, float* __restrict__ s1p, float* __restrict__ s2p) {
    __shared__ __align__(16) ushort As[128 * BK];
    __shared__ __align__(16) ushort Bs[128 * BK];
    __shared__ float sb1[4][64];
    __shared__ float sb2[4][64];
    const int tid = threadIdx.x;
    const int lane = tid & 63;
    const int w = tid >> 6;
    const int rowBase = blockIdx.y * 128;
    const int colBase = blockIdx.x * 128;
    const int m0 = (w & 1) * 64;
    const int n0 = (w >> 1) * 64;

    f32x4 acc[4][4];
#pragma unroll
    for (int mi = 0; mi < 4; ++mi)
#pragma unroll
        for (int ni = 0; ni < 4; ++ni) acc[mi][ni] = (f32x4){0.f, 0.f, 0.f, 0.f};

    const int i0 = w * 128 + lane;
    const int i1 = i0 + 64;
    const int r0i = i0 >> 2, c0i = i0 & 3;
    const int r1i = i1 >> 2, c1i = i1 & 3;
    ushort* ldsA0 = As + w * 1024;
    ushort* ldsA1 = As + w * 1024 + 512;
    ushort* ldsB0 = Bs + w * 1024;
    ushort* ldsB1 = Bs + w * 1024 + 512;
    const int la = lane & 15, q = lane >> 4;

    for (int pass = 0; pass < 2; ++pass) {
        const ushort* A  = pass ? A2 : A1;
        const ushort* Bt = pass ? B2t : B1t;
        const int K   = pass ? K2 : K1;
        const int lda = pass ? lda2 : lda1;
        const int ldb = pass ? ldb2 : ldb1;
        if (A == nullptr) continue;
        const ushort* gA0 = A + (size_t)(rowBase + r0i) * lda + c0i * 8;
        const ushort* gA1 = A + (size_t)(rowBase + r1i) * lda + c1i * 8;
        const ushort* gB0 = Bt + (size_t)(colBase + r0i) * ldb + c0i * 8;
        const ushort* gB1 = Bt + (size_t)(colBase + r1i) * ldb + c1i * 8;
        for (int kt = 0; kt < K; kt += BK) {
            gll16(gA0 + kt, ldsA0);
            gll16(gA1 + kt, ldsA1);
            gll16(gB0 + kt, ldsB0);
            gll16(gB1 + kt, ldsB1);
            __syncthreads();
            bf16x8 av[4], bv[4];
#pragma unroll
            for (int mi = 0; mi < 4; ++mi)
                av[mi] = *(const bf16x8*)&As[(m0 + mi * 16 + la) * BK + q * 8];
#pragma unroll
            for (int ni = 0; ni < 4; ++ni)
                bv[ni] = *(const bf16x8*)&Bs[(n0 + ni * 16 + la) * BK + q * 8];
#pragma unroll
            for (int mi = 0; mi < 4; ++mi)
#pragma unroll
                for (int ni = 0; ni < 4; ++ni)
                    acc[mi][ni] = __builtin_amdgcn_mfma_f32_16x16x32_bf16(
                        av[mi], bv[ni], acc[mi][ni], 0, 0, 0);
            __syncthreads();
        }
    }

    // ---- C store (C/D layout: col = lane&15, row = q*4 + reg) ----
#pragma unroll
    for (int mi = 0; mi < 4; ++mi) {
#pragma unroll
        for (int ni = 0; ni < 4; ++ni) {
            const int lc = colBase + n0 + ni * 16 + la;
            const float bv = bias ? bias[lc] : 0.f;
#pragma unroll
            for (int r = 0; r < 4; ++r) {
                const int row = rowBase + m0 + mi * 16 + q * 4 + r;
                float v = acc[mi][ni][r] + bv;
                if (fuse_lrelu) v = v > 0.f ? v : SLOPE * v;
                if (Cbf) Cbf[(size_t)row * ldc + lc] = f2us(v);
                else     Cf[(size_t)row * ldc + lc] = v;
            }
        }
    }

    // ---- fused BN partial stats (pre-activation, fp32 exact) ----
    if (s1p) {
#pragma unroll
        for (int ni = 0; ni < 4; ++ni) {
            const int lc = colBase + n0 + ni * 16 + la;
            const float bv = bias ? bias[lc] : 0.f;
            float t1 = 0.f, t2 = 0.f;
#pragma unroll
            for (int mi = 0; mi < 4; ++mi)
#pragma unroll
                for (int r = 0; r < 4; ++r) {
                    float v = acc[mi][ni][r] + bv;
                    t1 += v;
                    t2 += v * v;
                }
            t1 += __shfl_xor(t1, 16);
            t1 += __shfl_xor(t1, 32);
            t2 += __shfl_xor(t2, 16);
            t2 += __shfl_xor(t2, 32);
            if (q == 0) {
                sb1[w][ni * 16 + la] = t1;
                sb2[w][ni * 16 + la] = t2;
            }
        }
        __syncthreads();
        if (tid < 128) {
            int half = tid >> 6, j = tid & 63;
            float v1 = sb1[2 * half][j] + sb1[2 * half + 1][j];
            float v2 = sb2[2 * half][j] + sb2[2 * half + 1][j];
            size_t o = (size_t)blockIdx.y * ldc + colBase + half * 64 + j;
            s1p[o] = v1;
            s2p[o] = v2;
        }
    }
}

// ---------------- BatchNorm finalize ----------------

__global__ void k_bn_finalize(const float* __restrict__ p1, const float* __restrict__ p2,
                              const float* __restrict__ gamma, const float* __restrict__ beta,
                              float* __restrict__ scale, float* __restrict__ shift) {
    int c = blockIdx.x * 256 + threadIdx.x;
    if (c >= HID) return;
    float s1 = 0.f, s2 = 0.f;
    for (int rb = 0; rb < MR; ++rb) {
        s1 += p1[(size_t)rb * HID + c];
        s2 += p2[(size_t)rb * HID + c];
    }
    float mean = s1 * (1.f / (float)NN);
    float var = s2 * (1.f / (float)NN) - mean * mean;
    var = fmaxf(var, 0.f);
    float sc = gamma[c] * rsqrtf(var + EPS);
    scale[c] = sc;
    shift[c] = beta[c] - mean * sc;
}

// ---------------- fused BN + pooling ----------------
// grid (HID/256, 128): rows 64..127 write zero padding for the head GEMM.

__global__ void k_poolbn(const ushort* __restrict__ Ybf,
                         const float* __restrict__ scale, const float* __restrict__ shift,
                         const int* __restrict__ gstart, ushort* __restrict__ hgbf) {
    int g = blockIdx.y;
    int col = blockIdx.x * 256 + threadIdx.x;
    if (g >= GG) {
        hgbf[(size_t)g * HID + col] = 0;
        return;
    }
    int s = gstart[g], e = gstart[g + 1];
    float sc = scale[col], sh = shift[col];
    float acc = 0.f;
    for (int n = s; n < e; ++n) {
        float v = sc * us2f(Ybf[(size_t)n * HID + col]) + sh;
        acc += v > 0.f ? v : SLOPE * v;
    }
    hgbf[(size_t)g * HID + col] = f2us(acc / fmaxf((float)(e - s), 1.f));
}

__global__ void k_gstart(const int* __restrict__ gid, int* __restrict__ gstart) {
    int g = threadIdx.x;
    if (g > GG) return;
    int lo = 0, hi = NN;
    while (lo < hi) {
        int mid = (lo + hi) >> 1;
        if (gid[mid] < g) lo = mid + 1; else hi = mid;
    }
    gstart[g] = lo;
}

__global__ void k_fc3(const float* __restrict__ x2, const float* __restrict__ W,
                      const float* __restrict__ b, float* __restrict__ out) {
    int g = blockIdx.x;
    int tid = threadIdx.x;
    float part[NCLS];
#pragma unroll
    for (int c = 0; c < NCLS; ++c) part[c] = 0.f;
    for (int k = tid; k < MID; k += 256) {
        float x = x2[(size_t)g * MID + k];
        const float* wr = W + (size_t)k * NCLS;
#pragma unroll
        for (int c = 0; c < NCLS; ++c) part[c] += x * wr[c];
    }
    __shared__ float red[4][NCLS];
    int lane = tid & 63, w = tid >> 6;
#pragma unroll
    for (int c = 0; c < NCLS; ++c) {
        float v = part[c];
        for (int o = 32; o > 0; o >>= 1) v += __shfl_down(v, o, 64);
        if (lane == 0) red[w][c] = v;
    }
    __syncthreads();
    if (tid < NCLS)
        out[(size_t)g * NCLS + tid] = red[0][tid] + red[1][tid] + red[2][tid] + red[3][tid] + b[tid];
}

// ---------------- launcher ----------------

extern "C" void kernel_launch(void* const* d_in, const int* in_sizes, int n_in,
                              void* d_out, int out_size, void* d_ws, size_t ws_size,
                              hipStream_t stream) {
    const float* h        = (const float*)d_in[0];
    const int*   src      = (const int*)d_in[1];
    const int*   dst      = (const int*)d_in[2];
    const int*   graph_id = (const int*)d_in[3];
    const float* Ws1 = (const float*)d_in[4];
    const float* Wn1 = (const float*)d_in[5];
    const float* b1  = (const float*)d_in[6];
    const float* Ws2 = (const float*)d_in[7];
    const float* Wn2 = (const float*)d_in[8];
    const float* b2  = (const float*)d_in[9];
    const float* Ws3 = (const float*)d_in[10];
    const float* Wn3 = (const float*)d_in[11];
    const float* b3  = (const float*)d_in[12];
    const float* g1  = (const float*)d_in[13];
    const float* be1 = (const float*)d_in[14];
    const float* g2  = (const float*)d_in[15];
    const float* be2 = (const float*)d_in[16];
    const float* g3  = (const float*)d_in[17];
    const float* be3 = (const float*)d_in[18];
    const float* fc1_w = (const float*)d_in[19];
    const float* fc1_b = (const float*)d_in[20];
    const float* fc2_w = (const float*)d_in[21];
    const float* fc2_b = (const float*)d_in[22];
    const float* fc3_w = (const float*)d_in[23];
    const float* fc3_b = (const float*)d_in[24];
    float* out = (float*)d_out;

    size_t off_b = 0;
    auto alloc = [&](size_t bytes) -> void* {
        void* p = (char*)d_ws + off_b;
        off_b += (bytes + 255) & ~(size_t)255;
        return p;
    };
    ushort* Wt0    = (ushort*)alloc((size_t)2 * HID * HID * 2);  // 16 MiB (2 slots)
    ushort* Wt1    = Wt0 + (size_t)HID * HID;
    ushort* X      = (ushort*)alloc((size_t)NN * HID * 2);       // 64 MiB
    ushort* AggX   = (ushort*)alloc((size_t)NN * HID * 2);       // 64 MiB
    ushort* Ybf    = (ushort*)alloc((size_t)NN * HID * 2);       // 64 MiB
    float*  deg    = (float*)alloc((size_t)NN * 4);
    int*    csroff = (int*)alloc((size_t)(NN + 1) * 4);
    int*    cursor = (int*)alloc((size_t)NN * 4);
    int*    csrsrc = (int*)alloc((size_t)EE * 4);
    float*  p1     = (float*)alloc((size_t)MR * HID * 4);        // 1 MiB
    float*  p2     = (float*)alloc((size_t)MR * HID * 4);        // 1 MiB
    float*  bnsc   = (float*)alloc((size_t)HID * 4);
    float*  bnsh   = (float*)alloc((size_t)HID * 4);
    int*    gstart = (int*)alloc((size_t)(GG + 1) * 4);
    // total ~211 MiB

    ushort* hbf  = AggX;                       // layer-1 A inputs in AggX region (dead after GEMM-L1)
    ushort* nmbf = AggX + (size_t)NN * 64;
    // head buffers carved from AggX region (dead after GEMM-L3). Ybf stays
    // live until k_poolbn so nothing may alias it.
    ushort* hgbf = AggX;                                   // [128,HID] bf16, 512 KiB
    ushort* x1bf = AggX + (size_t)128 * HID;               // [128,HID] bf16
    float*  x2f  = (float*)(AggX + (size_t)2 * 128 * HID); // [128,MID] fp32

    // ---- CSR build ----
    k_zero_i<<<dim3(NN / 256), dim3(256), 0, stream>>>(cursor, NN);
    k_count<<<dim3(EE / 256), dim3(256), 0, stream>>>(dst, cursor);
    k_scan<<<dim3(1), dim3(1024), 0, stream>>>(cursor, csroff, deg);
    k_zero_i<<<dim3(NN / 256), dim3(256), 0, stream>>>(cursor, NN);
    k_fill<<<dim3(EE / 256), dim3(256), 0, stream>>>(src, dst, csroff, cursor, csrsrc);
    k_gstart<<<dim3(1), dim3(128), 0, stream>>>(graph_id, gstart);

    // GEMM + finalize for one layer (writes Ybf + bnsc/bnsh)
    auto runGemmBN = [&](const ushort* A1, int lda1, int K1,
                         const ushort* A2, int lda2, int K2,
                         const float* Ws, const float* Wn, int Kw, int Kp,
                         const float* b, const float* gamma, const float* beta) {
        k_wt2<<<dim3(HID / 32, Kp / 32, 2), dim3(256), 0, stream>>>(Ws, Wn, Kw, HID, Wt0, Wt1, Kp);
        k_mgemm<<<dim3(HID / 128, NN / 128), dim3(256), 0, stream>>>(
            A1, lda1, Wt0, Kp, K1,
            A2, lda2, Wt1, Kp, K2,
            b, (float*)nullptr, Ybf, HID, 0, p1, p2);
        k_bn_finalize<<<dim3(HID / 256), dim3(256), 0, stream>>>(p1, p2, gamma, beta, bnsc, bnsh);
    };

    // ---- layer 1: K = 64 + 64 (padded from 63) ----
    k_h2bf<<<dim3(NN * 64 / 256), dim3(256), 0, stream>>>(h, hbf);
    k_agg_small<<<dim3(NN), dim3(64), 0, stream>>>(h, nmbf, csroff, csrsrc, deg);
    runGemmBN(hbf, 64, 64, nmbf, 64, 64, Ws1, Wn1, INF, 64, b1, g1, be1);
    // fused BN-apply + aggregation -> X, AggX (clobbers hbf/nmbf: dead)
    k_aggbn<<<dim3(NN), dim3(256), 0, stream>>>(Ybf, bnsc, bnsh, X, AggX, csroff, csrsrc, deg);

    // ---- layer 2: K = 2048 + 2048 merged ----
    runGemmBN(X, HID, HID, AggX, HID, HID, Ws2, Wn2, HID, HID, b2, g2, be2);
    k_aggbn<<<dim3(NN), dim3(256), 0, stream>>>(Ybf, bnsc, bnsh, X, AggX, csroff, csrsrc, deg);

    // ---- layer 3 ----
    runGemmBN(X, HID, HID, AggX, HID, HID, Ws3, Wn3, HID, HID, b3, g3, be3);

    // ---- fused BN + pooling (reads Ybf directly; writes padded bf16 hg) ----
    k_poolbn<<<dim3(HID / 256, 128), dim3(256), 0, stream>>>(Ybf, bnsc, bnsh, gstart, hgbf);

    // ---- MLP head ----
    k_wt2<<<dim3(HID / 32, HID / 32, 1), dim3(256), 0, stream>>>(fc1_w, fc1_w, HID, HID, Wt0, Wt0, HID);
    k_wt2<<<dim3(MID / 32, HID / 32, 1), dim3(256), 0, stream>>>(fc2_w, fc2_w, HID, MID, Wt1, Wt1, HID);
    k_mgemm<<<dim3(HID / 128, 1), dim3(256), 0, stream>>>(
        hgbf, HID, Wt0, HID, HID,
        (const ushort*)nullptr, 0, (const ushort*)nullptr, 0, 0,
        fc1_b, (float*)nullptr, x1bf, HID, 1, (float*)nullptr, (float*)nullptr);
    k_mgemm<<<dim3(MID / 128, 1), dim3(256), 0, stream>>>(
        x1bf, HID, Wt1, HID, HID,
        (const ushort*)nullptr, 0, (const ushort*)nullptr, 0, 0,
        fc2_b, x2f, (ushort*)nullptr, MID, 1, (float*)nullptr, (float*)nullptr);
    k_fc3<<<dim3(GG), dim3(256), 0, stream>>>(x2f, fc3_w, fc3_b, out);
}

// Round 7
// 1297.207 us; speedup vs baseline: 1.4293x; 1.0216x over previous
//
#include <hip/hip_runtime.h>
#include <hip/hip_bf16.h>

#define NN   16384
#define EE   65536
#define GG   64
#define INF  63
#define HID  2048
#define MID  1024
#define NCLS 18
#define EPS  1e-5f
#define SLOPE 0.01f
#define MR   (NN / 128)   // 128 block-rows for BN partials
#define KC   (2 * HID)    // concatenated K for wide layers

typedef unsigned short ushort;
typedef unsigned int uint;

using bf16x8 = __attribute__((ext_vector_type(8))) __bf16;
using f32x4  = __attribute__((ext_vector_type(4))) float;

__device__ __forceinline__ ushort f2us(float x) {
    __hip_bfloat16 b = __float2bfloat16(x);
    return __builtin_bit_cast(ushort, b);
}
__device__ __forceinline__ float us2f(ushort u) {
    return __bfloat162float(__builtin_bit_cast(__hip_bfloat16, u));
}

// async global->LDS, 16B per lane; LDS base wave-uniform, HW adds lane*16
__device__ __forceinline__ void gll16(const ushort* g, ushort* l) {
    __builtin_amdgcn_global_load_lds(
        (const __attribute__((address_space(1))) uint*)g,
        (__attribute__((address_space(3))) uint*)l, 16, 0, 0);
}

// ---------------- utility ----------------

__global__ void k_zero_i(int* __restrict__ p, int n) {
    int i = blockIdx.x * blockDim.x + threadIdx.x;
    if (i < n) p[i] = 0;
}

// ---------------- CSR build (by dst) ----------------

__global__ void k_count(const int* __restrict__ dst, int* __restrict__ cnt) {
    int e = blockIdx.x * blockDim.x + threadIdx.x;
    if (e < EE) atomicAdd(&cnt[dst[e]], 1);
}

__global__ void k_scan(const int* __restrict__ cnt, int* __restrict__ off,
                       float* __restrict__ deg) {
    __shared__ int sh[1024];
    int t = threadIdx.x;
    int base = t * 16;
    int loc[16];
    int s = 0;
#pragma unroll
    for (int i = 0; i < 16; ++i) {
        int c = cnt[base + i];
        loc[i] = s;
        s += c;
        deg[base + i] = (float)c;
    }
    sh[t] = s;
    __syncthreads();
    for (int d = 1; d < 1024; d <<= 1) {
        int v = (t >= d) ? sh[t - d] : 0;
        __syncthreads();
        sh[t] += v;
        __syncthreads();
    }
    int excl = sh[t] - s;
#pragma unroll
    for (int i = 0; i < 16; ++i) off[base + i] = excl + loc[i];
    if (t == 1023) off[NN] = sh[1023];
}

__global__ void k_fill(const int* __restrict__ src, const int* __restrict__ dst,
                       const int* __restrict__ off, int* __restrict__ cur,
                       int* __restrict__ csr_src) {
    int e = blockIdx.x * blockDim.x + threadIdx.x;
    if (e < EE) {
        int d = dst[e];
        int p = atomicAdd(&cur[d], 1);
        csr_src[off[d] + p] = src[e];
    }
}

// ---------------- layer-1 prep (into concat [NN,128]) ----------------

__global__ void k_h2bf_c(const float* __restrict__ h, ushort* __restrict__ Xc) {
    int i = blockIdx.x * 256 + threadIdx.x;  // over NN*64
    int r = i >> 6, c = i & 63;
    Xc[(size_t)r * 128 + c] = (c < INF) ? f2us(h[(size_t)r * INF + c]) : (ushort)0;
}

__global__ void k_agg_small_c(const float* __restrict__ X, ushort* __restrict__ Xc,
                              const int* __restrict__ off, const int* __restrict__ csr_src,
                              const float* __restrict__ deg) {
    int v = blockIdx.x;
    int f = threadIdx.x;  // 64
    float acc = 0.f;
    if (f < INF) {
        int s = off[v], e = off[v + 1];
        for (int i = s; i < e; ++i) acc += X[(size_t)csr_src[i] * INF + f];
        acc /= fmaxf(deg[v], 1.f);
    }
    Xc[(size_t)v * 128 + 64 + f] = f2us(acc);
}

// ---------------- fused BN-apply + aggregation (into concat [NN,KC]) -------
// Xc[v][0:2048]   = bf16(lrelu(sc*Ybf[v]+sh))
// Xc[v][2048:4096]= bf16(mean_nb lrelu(sc*Ybf[u]+sh))  (fp32 accum)

__global__ void k_aggbn_c(const ushort* __restrict__ Ybf,
                          const float* __restrict__ sc8, const float* __restrict__ sh8,
                          ushort* __restrict__ Xc,
                          const int* __restrict__ off, const int* __restrict__ csr_src,
                          const float* __restrict__ deg) {
    int v = blockIdx.x;
    int t = threadIdx.x;
    int c = t * 8;
    float sc[8], sh[8];
    *(float4*)&sc[0] = *(const float4*)&sc8[c];
    *(float4*)&sc[4] = *(const float4*)&sc8[c + 4];
    *(float4*)&sh[0] = *(const float4*)&sh8[c];
    *(float4*)&sh[4] = *(const float4*)&sh8[c + 4];

    // own row
    {
        uint4 u = ((const uint4*)(Ybf + (size_t)v * HID))[t];
        uint wds[4] = {u.x, u.y, u.z, u.w};
        uint o[4];
#pragma unroll
        for (int j = 0; j < 4; ++j) {
            float a = sc[2 * j] * us2f((ushort)(wds[j] & 0xffffu)) + sh[2 * j];
            float b = sc[2 * j + 1] * us2f((ushort)(wds[j] >> 16)) + sh[2 * j + 1];
            a = a > 0.f ? a : SLOPE * a;
            b = b > 0.f ? b : SLOPE * b;
            o[j] = (uint)f2us(a) | ((uint)f2us(b) << 16);
        }
        ((uint4*)(Xc + (size_t)v * KC))[t] = make_uint4(o[0], o[1], o[2], o[3]);
    }

    // neighbor mean
    int s = off[v], e = off[v + 1];
    float acc[8];
#pragma unroll
    for (int j = 0; j < 8; ++j) acc[j] = 0.f;
    for (int i = s; i < e; ++i) {
        uint4 u = ((const uint4*)(Ybf + (size_t)csr_src[i] * HID))[t];
        uint wds[4] = {u.x, u.y, u.z, u.w};
#pragma unroll
        for (int j = 0; j < 4; ++j) {
            float a = sc[2 * j] * us2f((ushort)(wds[j] & 0xffffu)) + sh[2 * j];
            float b = sc[2 * j + 1] * us2f((ushort)(wds[j] >> 16)) + sh[2 * j + 1];
            acc[2 * j]     += a > 0.f ? a : SLOPE * a;
            acc[2 * j + 1] += b > 0.f ? b : SLOPE * b;
        }
    }
    float inv = 1.f / fmaxf(deg[v], 1.f);
    uint o[4];
#pragma unroll
    for (int j = 0; j < 4; ++j)
        o[j] = (uint)f2us(acc[2 * j] * inv) | ((uint)f2us(acc[2 * j + 1] * inv) << 16);
    ((uint4*)(Xc + (size_t)v * KC + HID))[t] = make_uint4(o[0], o[1], o[2], o[3]);
}

// ---------------- weight transposes ----------------
// concat pair: z=0 -> Ws into k-cols [0,KP/2), z=1 -> Wn into [KP/2,KP)
__global__ void k_wt2c(const float* __restrict__ W0, const float* __restrict__ W1,
                       int Kw, int N, ushort* __restrict__ Wtc, int KP) {
    const float* W = blockIdx.z ? W1 : W0;
    const int kOff = blockIdx.z ? (KP / 2) : 0;
    __shared__ float t[32][33];
    int kb = blockIdx.y * 32, nb = blockIdx.x * 32;
    int tx = threadIdx.x & 31, ty = threadIdx.x >> 5;
#pragma unroll
    for (int i = 0; i < 32; i += 8) {
        int k = kb + ty + i;
        t[ty + i][tx] = (k < Kw) ? W[(size_t)k * N + nb + tx] : 0.f;
    }
    __syncthreads();
#pragma unroll
    for (int i = 0; i < 32; i += 8)
        Wtc[(size_t)(nb + ty + i) * KP + kOff + kb + tx] = f2us(t[tx][ty + i]);
}

// single: Wt[n][k] = bf16(W[k][n])
__global__ void k_wt(const float* __restrict__ W, int K, int N,
                     ushort* __restrict__ Wt, int Kp) {
    __shared__ float t[32][33];
    int kb = blockIdx.y * 32, nb = blockIdx.x * 32;
    int tx = threadIdx.x & 31, ty = threadIdx.x >> 5;
#pragma unroll
    for (int i = 0; i < 32; i += 8) {
        int k = kb + ty + i;
        t[ty + i][tx] = (k < K) ? W[(size_t)k * N + nb + tx] : 0.f;
    }
    __syncthreads();
#pragma unroll
    for (int i = 0; i < 32; i += 8)
        Wt[(size_t)(nb + ty + i) * Kp + kb + tx] = f2us(t[tx][ty + i]);
}

// ---------------- MFMA GEMM (m97 structure, single-pass, fused BN partials)
// C = A@Bt^T + bias; A bf16 [M,K] lda, Bt bf16 [N,K] ldb. 128x128 tile,
// BK=32, 256 thr (4 waves), wave = 64x64 quadrant of 4x4 mfma 16x16x32.
// Split-K via blockIdx.z: A/Bt advance z*K columns, Cf advances z*cStrideZ.

#define BK 32

__global__ __launch_bounds__(256)
void k_mgemm(const ushort* __restrict__ A, int lda, const ushort* __restrict__ Bt, int ldb,
             int K, const float* __restrict__ bias, float* __restrict__ Cf,
             ushort* __restrict__ Cbf, int ldc, int fuse_lrelu,
             float* __restrict__ s1p, float* __restrict__ s2p, size_t cStrideZ) {
    __shared__ __align__(16) ushort As[128 * BK];
    __shared__ __align__(16) ushort Bs[128 * BK];
    __shared__ float sb1[4][64];
    __shared__ float sb2[4][64];
    const int tid = threadIdx.x;
    const int lane = tid & 63;
    const int w = tid >> 6;
    const int rowBase = blockIdx.y * 128;
    const int colBase = blockIdx.x * 128;
    const int m0 = (w & 1) * 64;
    const int n0 = (w >> 1) * 64;
    const int z = blockIdx.z;
    A += (size_t)z * K;
    Bt += (size_t)z * K;
    if (Cf) Cf += (size_t)z * cStrideZ;

    f32x4 acc[4][4];
#pragma unroll
    for (int mi = 0; mi < 4; ++mi)
#pragma unroll
        for (int ni = 0; ni < 4; ++ni) acc[mi][ni] = (f32x4){0.f, 0.f, 0.f, 0.f};

    const int i0 = w * 128 + lane;
    const int i1 = i0 + 64;
    const int r0i = i0 >> 2, c0i = i0 & 3;
    const int r1i = i1 >> 2, c1i = i1 & 3;
    ushort* ldsA0 = As + w * 1024;
    ushort* ldsA1 = As + w * 1024 + 512;
    ushort* ldsB0 = Bs + w * 1024;
    ushort* ldsB1 = Bs + w * 1024 + 512;
    const int la = lane & 15, q = lane >> 4;

    const ushort* gA0 = A + (size_t)(rowBase + r0i) * lda + c0i * 8;
    const ushort* gA1 = A + (size_t)(rowBase + r1i) * lda + c1i * 8;
    const ushort* gB0 = Bt + (size_t)(colBase + r0i) * ldb + c0i * 8;
    const ushort* gB1 = Bt + (size_t)(colBase + r1i) * ldb + c1i * 8;
    for (int kt = 0; kt < K; kt += BK) {
        gll16(gA0 + kt, ldsA0);
        gll16(gA1 + kt, ldsA1);
        gll16(gB0 + kt, ldsB0);
        gll16(gB1 + kt, ldsB1);
        __syncthreads();
        bf16x8 av[4], bv[4];
#pragma unroll
        for (int mi = 0; mi < 4; ++mi)
            av[mi] = *(const bf16x8*)&As[(m0 + mi * 16 + la) * BK + q * 8];
#pragma unroll
        for (int ni = 0; ni < 4; ++ni)
            bv[ni] = *(const bf16x8*)&Bs[(n0 + ni * 16 + la) * BK + q * 8];
#pragma unroll
        for (int mi = 0; mi < 4; ++mi)
#pragma unroll
            for (int ni = 0; ni < 4; ++ni)
                acc[mi][ni] = __builtin_amdgcn_mfma_f32_16x16x32_bf16(
                    av[mi], bv[ni], acc[mi][ni], 0, 0, 0);
        __syncthreads();
    }

    // ---- C store (C/D layout: col = lane&15, row = q*4 + reg) ----
#pragma unroll
    for (int mi = 0; mi < 4; ++mi) {
#pragma unroll
        for (int ni = 0; ni < 4; ++ni) {
            const int lc = colBase + n0 + ni * 16 + la;
            const float bv = bias ? bias[lc] : 0.f;
#pragma unroll
            for (int r = 0; r < 4; ++r) {
                const int row = rowBase + m0 + mi * 16 + q * 4 + r;
                float v = acc[mi][ni][r] + bv;
                if (fuse_lrelu) v = v > 0.f ? v : SLOPE * v;
                if (Cbf) Cbf[(size_t)row * ldc + lc] = f2us(v);
                else     Cf[(size_t)row * ldc + lc] = v;
            }
        }
    }

    // ---- fused BN partial stats (pre-activation, fp32 exact) ----
    if (s1p) {
#pragma unroll
        for (int ni = 0; ni < 4; ++ni) {
            const int lc = colBase + n0 + ni * 16 + la;
            const float bv = bias ? bias[lc] : 0.f;
            float t1 = 0.f, t2 = 0.f;
#pragma unroll
            for (int mi = 0; mi < 4; ++mi)
#pragma unroll
                for (int r = 0; r < 4; ++r) {
                    float v = acc[mi][ni][r] + bv;
                    t1 += v;
                    t2 += v * v;
                }
            t1 += __shfl_xor(t1, 16);
            t1 += __shfl_xor(t1, 32);
            t2 += __shfl_xor(t2, 16);
            t2 += __shfl_xor(t2, 32);
            if (q == 0) {
                sb1[w][ni * 16 + la] = t1;
                sb2[w][ni * 16 + la] = t2;
            }
        }
        __syncthreads();
        if (tid < 128) {
            int half = tid >> 6, j = tid & 63;
            float v1 = sb1[2 * half][j] + sb1[2 * half + 1][j];
            float v2 = sb2[2 * half][j] + sb2[2 * half + 1][j];
            size_t o = (size_t)blockIdx.y * ldc + colBase + half * 64 + j;
            s1p[o] = v1;
            s2p[o] = v2;
        }
    }
}

// ---------------- BatchNorm finalize ----------------

__global__ void k_bn_finalize(const float* __restrict__ p1, const float* __restrict__ p2,
                              const float* __restrict__ gamma, const float* __restrict__ beta,
                              float* __restrict__ scale, float* __restrict__ shift) {
    int c = blockIdx.x * 256 + threadIdx.x;
    if (c >= HID) return;
    float s1 = 0.f, s2 = 0.f;
    for (int rb = 0; rb < MR; ++rb) {
        s1 += p1[(size_t)rb * HID + c];
        s2 += p2[(size_t)rb * HID + c];
    }
    float mean = s1 * (1.f / (float)NN);
    float var = s2 * (1.f / (float)NN) - mean * mean;
    var = fmaxf(var, 0.f);
    float sc = gamma[c] * rsqrtf(var + EPS);
    scale[c] = sc;
    shift[c] = beta[c] - mean * sc;
}

// ---------------- fused BN + pooling ----------------

__global__ void k_poolbn(const ushort* __restrict__ Ybf,
                         const float* __restrict__ scale, const float* __restrict__ shift,
                         const int* __restrict__ gstart, ushort* __restrict__ hgbf) {
    int g = blockIdx.y;
    int col = blockIdx.x * 256 + threadIdx.x;
    if (g >= GG) {
        hgbf[(size_t)g * HID + col] = 0;
        return;
    }
    int s = gstart[g], e = gstart[g + 1];
    float sc = scale[col], sh = shift[col];
    float acc = 0.f;
    for (int n = s; n < e; ++n) {
        float v = sc * us2f(Ybf[(size_t)n * HID + col]) + sh;
        acc += v > 0.f ? v : SLOPE * v;
    }
    hgbf[(size_t)g * HID + col] = f2us(acc / fmaxf((float)(e - s), 1.f));
}

__global__ void k_gstart(const int* __restrict__ gid, int* __restrict__ gstart) {
    int g = threadIdx.x;
    if (g > GG) return;
    int lo = 0, hi = NN;
    while (lo < hi) {
        int mid = (lo + hi) >> 1;
        if (gid[mid] < g) lo = mid + 1; else hi = mid;
    }
    gstart[g] = lo;
}

// ---------------- split-K reduce for head GEMMs ----------------
// out[i] = act(sum_p part[p*strideZ + i] + bias[i % ldc])

__global__ void k_redhead(const float* __restrict__ part, int P, size_t strideZ,
                          const float* __restrict__ bias, int ldc,
                          ushort* __restrict__ obf, float* __restrict__ of, int n) {
    int i = blockIdx.x * 256 + threadIdx.x;
    if (i >= n) return;
    float s = 0.f;
    for (int p = 0; p < P; ++p) s += part[(size_t)p * strideZ + i];
    s += bias[i % ldc];
    s = s > 0.f ? s : SLOPE * s;
    if (obf) obf[i] = f2us(s);
    else     of[i] = s;
}

__global__ void k_fc3(const float* __restrict__ x2, const float* __restrict__ W,
                      const float* __restrict__ b, float* __restrict__ out) {
    int g = blockIdx.x;
    int tid = threadIdx.x;
    float part[NCLS];
#pragma unroll
    for (int c = 0; c < NCLS; ++c) part[c] = 0.f;
    for (int k = tid; k < MID; k += 256) {
        float x = x2[(size_t)g * MID + k];
        const float* wr = W + (size_t)k * NCLS;
#pragma unroll
        for (int c = 0; c < NCLS; ++c) part[c] += x * wr[c];
    }
    __shared__ float red[4][NCLS];
    int lane = tid & 63, w = tid >> 6;
#pragma unroll
    for (int c = 0; c < NCLS; ++c) {
        float v = part[c];
        for (int o = 32; o > 0; o >>= 1) v += __shfl_down(v, o, 64);
        if (lane == 0) red[w][c] = v;
    }
    __syncthreads();
    if (tid < NCLS)
        out[(size_t)g * NCLS + tid] = red[0][tid] + red[1][tid] + red[2][tid] + red[3][tid] + b[tid];
}

// ---------------- launcher ----------------

extern "C" void kernel_launch(void* const* d_in, const int* in_sizes, int n_in,
                              void* d_out, int out_size, void* d_ws, size_t ws_size,
                              hipStream_t stream) {
    const float* h        = (const float*)d_in[0];
    const int*   src      = (const int*)d_in[1];
    const int*   dst      = (const int*)d_in[2];
    const int*   graph_id = (const int*)d_in[3];
    const float* Ws1 = (const float*)d_in[4];
    const float* Wn1 = (const float*)d_in[5];
    const float* b1  = (const float*)d_in[6];
    const float* Ws2 = (const float*)d_in[7];
    const float* Wn2 = (const float*)d_in[8];
    const float* b2  = (const float*)d_in[9];
    const float* Ws3 = (const float*)d_in[10];
    const float* Wn3 = (const float*)d_in[11];
    const float* b3  = (const float*)d_in[12];
    const float* g1  = (const float*)d_in[13];
    const float* be1 = (const float*)d_in[14];
    const float* g2  = (const float*)d_in[15];
    const float* be2 = (const float*)d_in[16];
    const float* g3  = (const float*)d_in[17];
    const float* be3 = (const float*)d_in[18];
    const float* fc1_w = (const float*)d_in[19];
    const float* fc1_b = (const float*)d_in[20];
    const float* fc2_w = (const float*)d_in[21];
    const float* fc2_b = (const float*)d_in[22];
    const float* fc3_w = (const float*)d_in[23];
    const float* fc3_b = (const float*)d_in[24];
    float* out = (float*)d_out;

    size_t off_b = 0;
    auto alloc = [&](size_t bytes) -> void* {
        void* p = (char*)d_ws + off_b;
        off_b += (bytes + 255) & ~(size_t)255;
        return p;
    };
    ushort* Wtc    = (ushort*)alloc((size_t)HID * KC * 2);       // 16 MiB concat weights
    ushort* Xc     = (ushort*)alloc((size_t)NN * KC * 2);        // 128 MiB concat activations
    ushort* Ybf    = (ushort*)alloc((size_t)NN * HID * 2);       // 64 MiB
    float*  deg    = (float*)alloc((size_t)NN * 4);
    int*    csroff = (int*)alloc((size_t)(NN + 1) * 4);
    int*    cursor = (int*)alloc((size_t)NN * 4);
    int*    csrsrc = (int*)alloc((size_t)EE * 4);
    float*  p1     = (float*)alloc((size_t)MR * HID * 4);        // 1 MiB
    float*  p2     = (float*)alloc((size_t)MR * HID * 4);        // 1 MiB
    float*  bnsc   = (float*)alloc((size_t)HID * 4);
    float*  bnsh   = (float*)alloc((size_t)HID * 4);
    int*    gstart = (int*)alloc((size_t)(GG + 1) * 4);
    // total ~212 MiB

    // head weight slots inside Wtc (layers are done with it by then)
    ushort* WtH0 = Wtc;                            // fc1^T [2048,2048] 8 MiB
    ushort* WtH1 = Wtc + (size_t)HID * HID;        // fc2^T [1024,2048] 4 MiB
    // head scratch inside Xc (dead after layer-3 GEMM)
    ushort* hgbf  = Xc;                                     // [128,2048] bf16
    ushort* x1bf  = Xc + (size_t)128 * HID;                 // [128,2048] bf16
    float*  x2f   = (float*)(Xc + (size_t)2 * 128 * HID);   // [128,1024] fp32
    float*  partF = (float*)(Xc + (size_t)3 * 128 * HID);   // up to 4 MiB fp32 partials

    // ---- CSR build ----
    k_zero_i<<<dim3(NN / 256), dim3(256), 0, stream>>>(cursor, NN);
    k_count<<<dim3(EE / 256), dim3(256), 0, stream>>>(dst, cursor);
    k_scan<<<dim3(1), dim3(1024), 0, stream>>>(cursor, csroff, deg);
    k_zero_i<<<dim3(NN / 256), dim3(256), 0, stream>>>(cursor, NN);
    k_fill<<<dim3(EE / 256), dim3(256), 0, stream>>>(src, dst, csroff, cursor, csrsrc);
    k_gstart<<<dim3(1), dim3(128), 0, stream>>>(graph_id, gstart);

    // ---- layer 1: concat K=128 (cols 0..62 = h, 64..126 = Agg(h)) ----
    k_h2bf_c<<<dim3(NN * 64 / 256), dim3(256), 0, stream>>>(h, Xc);
    k_agg_small_c<<<dim3(NN), dim3(64), 0, stream>>>(h, Xc, csroff, csrsrc, deg);
    k_wt2c<<<dim3(HID / 32, 2, 2), dim3(256), 0, stream>>>(Ws1, Wn1, INF, HID, Wtc, 128);
    k_mgemm<<<dim3(HID / 128, NN / 128, 1), dim3(256), 0, stream>>>(
        Xc, 128, Wtc, 128, 128, b1, (float*)nullptr, Ybf, HID, 0, p1, p2, 0);
    k_bn_finalize<<<dim3(HID / 256), dim3(256), 0, stream>>>(p1, p2, g1, be1, bnsc, bnsh);
    k_aggbn_c<<<dim3(NN), dim3(256), 0, stream>>>(Ybf, bnsc, bnsh, Xc, csroff, csrsrc, deg);

    // ---- layer 2: single-pass K=4096 ----
    k_wt2c<<<dim3(HID / 32, HID / 32, 2), dim3(256), 0, stream>>>(Ws2, Wn2, HID, HID, Wtc, KC);
    k_mgemm<<<dim3(HID / 128, NN / 128, 1), dim3(256), 0, stream>>>(
        Xc, KC, Wtc, KC, KC, b2, (float*)nullptr, Ybf, HID, 0, p1, p2, 0);
    k_bn_finalize<<<dim3(HID / 256), dim3(256), 0, stream>>>(p1, p2, g2, be2, bnsc, bnsh);
    k_aggbn_c<<<dim3(NN), dim3(256), 0, stream>>>(Ybf, bnsc, bnsh, Xc, csroff, csrsrc, deg);

    // ---- layer 3 ----
    k_wt2c<<<dim3(HID / 32, HID / 32, 2), dim3(256), 0, stream>>>(Ws3, Wn3, HID, HID, Wtc, KC);
    k_mgemm<<<dim3(HID / 128, NN / 128, 1), dim3(256), 0, stream>>>(
        Xc, KC, Wtc, KC, KC, b3, (float*)nullptr, Ybf, HID, 0, p1, p2, 0);
    k_bn_finalize<<<dim3(HID / 256), dim3(256), 0, stream>>>(p1, p2, g3, be3, bnsc, bnsh);

    // ---- fused BN + pooling (Ybf -> padded bf16 hg in Xc region) ----
    k_poolbn<<<dim3(HID / 256, 128), dim3(256), 0, stream>>>(Ybf, bnsc, bnsh, gstart, hgbf);

    // ---- MLP head (split-K x4, deterministic two-stage) ----
    k_wt<<<dim3(HID / 32, HID / 32), dim3(256), 0, stream>>>(fc1_w, HID, HID, WtH0, HID);
    k_wt<<<dim3(MID / 32, HID / 32), dim3(256), 0, stream>>>(fc2_w, HID, MID, WtH1, HID);
    k_mgemm<<<dim3(HID / 128, 1, 4), dim3(256), 0, stream>>>(
        hgbf, HID, WtH0, HID, HID / 4, (const float*)nullptr,
        partF, (ushort*)nullptr, HID, 0, (float*)nullptr, (float*)nullptr,
        (size_t)128 * HID);
    k_redhead<<<dim3(128 * HID / 256), dim3(256), 0, stream>>>(
        partF, 4, (size_t)128 * HID, fc1_b, HID, x1bf, (float*)nullptr, 128 * HID);
    k_mgemm<<<dim3(MID / 128, 1, 4), dim3(256), 0, stream>>>(
        x1bf, HID, WtH1, HID, HID / 4, (const float*)nullptr,
        partF, (ushort*)nullptr, MID, 0, (float*)nullptr, (float*)nullptr,
        (size_t)128 * MID);
    k_redhead<<<dim3(128 * MID / 256), dim3(256), 0, stream>>>(
        partF, 4, (size_t)128 * MID, fc2_b, MID, (ushort*)nullptr, x2f, 128 * MID);
    k_fc3<<<dim3(GG), dim3(256), 0, stream>>>(x2f, fc3_w, fc3_b, out);
}

// Round 8
// 1252.979 us; speedup vs baseline: 1.4798x; 1.0353x over previous
//
#include <hip/hip_runtime.h>
#include <hip/hip_bf16.h>

#define NN   16384
#define EE   65536
#define GG   64
#define INF  63
#define HID  2048
#define MID  1024
#define NCLS 18
#define EPS  1e-5f
#define SLOPE 0.01f
#define MR   (NN / 128)   // 128 block-rows for BN partials

typedef unsigned short ushort;
typedef unsigned int uint;

using bf16x8 = __attribute__((ext_vector_type(8))) __bf16;
using f32x4  = __attribute__((ext_vector_type(4))) float;

__device__ __forceinline__ ushort f2us(float x) {
    __hip_bfloat16 b = __float2bfloat16(x);
    return __builtin_bit_cast(ushort, b);
}
__device__ __forceinline__ float us2f(ushort u) {
    return __bfloat162float(__builtin_bit_cast(__hip_bfloat16, u));
}

// async global->LDS, 16B per lane; LDS base wave-uniform, HW adds lane*16
__device__ __forceinline__ void gll16(const ushort* g, ushort* l) {
    __builtin_amdgcn_global_load_lds(
        (const __attribute__((address_space(1))) uint*)g,
        (__attribute__((address_space(3))) uint*)l, 16, 0, 0);
}

// ---------------- utility ----------------

__global__ void k_zero_i(int* __restrict__ p, int n) {
    int i = blockIdx.x * blockDim.x + threadIdx.x;
    if (i < n) p[i] = 0;
}

// ---------------- CSR build (by dst) ----------------

__global__ void k_count(const int* __restrict__ dst, int* __restrict__ cnt) {
    int e = blockIdx.x * blockDim.x + threadIdx.x;
    if (e < EE) atomicAdd(&cnt[dst[e]], 1);
}

__global__ void k_scan(const int* __restrict__ cnt, int* __restrict__ off,
                       float* __restrict__ deg) {
    __shared__ int sh[1024];
    int t = threadIdx.x;
    int base = t * 16;
    int loc[16];
    int s = 0;
#pragma unroll
    for (int i = 0; i < 16; ++i) {
        int c = cnt[base + i];
        loc[i] = s;
        s += c;
        deg[base + i] = (float)c;
    }
    sh[t] = s;
    __syncthreads();
    for (int d = 1; d < 1024; d <<= 1) {
        int v = (t >= d) ? sh[t - d] : 0;
        __syncthreads();
        sh[t] += v;
        __syncthreads();
    }
    int excl = sh[t] - s;
#pragma unroll
    for (int i = 0; i < 16; ++i) off[base + i] = excl + loc[i];
    if (t == 1023) off[NN] = sh[1023];
}

__global__ void k_fill(const int* __restrict__ src, const int* __restrict__ dst,
                       const int* __restrict__ off, int* __restrict__ cur,
                       int* __restrict__ csr_src) {
    int e = blockIdx.x * blockDim.x + threadIdx.x;
    if (e < EE) {
        int d = dst[e];
        int p = atomicAdd(&cur[d], 1);
        csr_src[off[d] + p] = src[e];
    }
}

// ---------------- layer-1 prep (into concat [NN,128]) ----------------

__global__ void k_h2bf_c(const float* __restrict__ h, ushort* __restrict__ Xc) {
    int i = blockIdx.x * 256 + threadIdx.x;  // over NN*64
    int r = i >> 6, c = i & 63;
    Xc[(size_t)r * 128 + c] = (c < INF) ? f2us(h[(size_t)r * INF + c]) : (ushort)0;
}

__global__ void k_agg_small_c(const float* __restrict__ X, ushort* __restrict__ Xc,
                              const int* __restrict__ off, const int* __restrict__ csr_src,
                              const float* __restrict__ deg) {
    int v = blockIdx.x;
    int f = threadIdx.x;  // 64
    float acc = 0.f;
    if (f < INF) {
        int s = off[v], e = off[v + 1];
        for (int i = s; i < e; ++i) acc += X[(size_t)csr_src[i] * INF + f];
        acc /= fmaxf(deg[v], 1.f);
    }
    Xc[(size_t)v * 128 + 64 + f] = f2us(acc);
}

// ---------------- fused BN-apply + aggregation ----------------
// X[v]    = bf16(lrelu(sc*Ybf[v]+sh))
// AggX[v] = bf16(mean_nb lrelu(sc*Ybf[u]+sh))  (fp32 accum)

__global__ void k_aggbn(const ushort* __restrict__ Ybf,
                        const float* __restrict__ sc8, const float* __restrict__ sh8,
                        ushort* __restrict__ X, ushort* __restrict__ AggX,
                        const int* __restrict__ off, const int* __restrict__ csr_src,
                        const float* __restrict__ deg) {
    int v = blockIdx.x;
    int t = threadIdx.x;
    int c = t * 8;
    float sc[8], sh[8];
    *(float4*)&sc[0] = *(const float4*)&sc8[c];
    *(float4*)&sc[4] = *(const float4*)&sc8[c + 4];
    *(float4*)&sh[0] = *(const float4*)&sh8[c];
    *(float4*)&sh[4] = *(const float4*)&sh8[c + 4];

    // own row
    {
        uint4 u = ((const uint4*)(Ybf + (size_t)v * HID))[t];
        uint wds[4] = {u.x, u.y, u.z, u.w};
        uint o[4];
#pragma unroll
        for (int j = 0; j < 4; ++j) {
            float a = sc[2 * j] * us2f((ushort)(wds[j] & 0xffffu)) + sh[2 * j];
            float b = sc[2 * j + 1] * us2f((ushort)(wds[j] >> 16)) + sh[2 * j + 1];
            a = a > 0.f ? a : SLOPE * a;
            b = b > 0.f ? b : SLOPE * b;
            o[j] = (uint)f2us(a) | ((uint)f2us(b) << 16);
        }
        ((uint4*)(X + (size_t)v * HID))[t] = make_uint4(o[0], o[1], o[2], o[3]);
    }

    // neighbor mean
    int s = off[v], e = off[v + 1];
    float acc[8];
#pragma unroll
    for (int j = 0; j < 8; ++j) acc[j] = 0.f;
    for (int i = s; i < e; ++i) {
        uint4 u = ((const uint4*)(Ybf + (size_t)csr_src[i] * HID))[t];
        uint wds[4] = {u.x, u.y, u.z, u.w};
#pragma unroll
        for (int j = 0; j < 4; ++j) {
            float a = sc[2 * j] * us2f((ushort)(wds[j] & 0xffffu)) + sh[2 * j];
            float b = sc[2 * j + 1] * us2f((ushort)(wds[j] >> 16)) + sh[2 * j + 1];
            acc[2 * j]     += a > 0.f ? a : SLOPE * a;
            acc[2 * j + 1] += b > 0.f ? b : SLOPE * b;
        }
    }
    float inv = 1.f / fmaxf(deg[v], 1.f);
    uint o[4];
#pragma unroll
    for (int j = 0; j < 4; ++j)
        o[j] = (uint)f2us(acc[2 * j] * inv) | ((uint)f2us(acc[2 * j + 1] * inv) << 16);
    ((uint4*)(AggX + (size_t)v * HID))[t] = make_uint4(o[0], o[1], o[2], o[3]);
}

// ---------------- weight transposes ----------------

// paired: z=0: W0 -> Wt0 ; z=1: W1 -> Wt1.  Wt[n][k] = bf16(W[k][n]), pad 0.
__global__ void k_wt2(const float* __restrict__ W0, const float* __restrict__ W1,
                      int K, int N, ushort* __restrict__ Wt0, ushort* __restrict__ Wt1,
                      int Kp) {
    const float* W = blockIdx.z ? W1 : W0;
    ushort* Wt = blockIdx.z ? Wt1 : Wt0;
    __shared__ float t[32][33];
    int kb = blockIdx.y * 32, nb = blockIdx.x * 32;
    int tx = threadIdx.x & 31, ty = threadIdx.x >> 5;
#pragma unroll
    for (int i = 0; i < 32; i += 8) {
        int k = kb + ty + i;
        t[ty + i][tx] = (k < K) ? W[(size_t)k * N + nb + tx] : 0.f;
    }
    __syncthreads();
#pragma unroll
    for (int i = 0; i < 32; i += 8)
        Wt[(size_t)(nb + ty + i) * Kp + kb + tx] = f2us(t[tx][ty + i]);
}

// concat pair into one [N,KP] buffer: z=0 -> k-cols [0,KP/2), z=1 -> [KP/2,KP)
__global__ void k_wt2c(const float* __restrict__ W0, const float* __restrict__ W1,
                       int Kw, int N, ushort* __restrict__ Wtc, int KP) {
    const float* W = blockIdx.z ? W1 : W0;
    const int kOff = blockIdx.z ? (KP / 2) : 0;
    __shared__ float t[32][33];
    int kb = blockIdx.y * 32, nb = blockIdx.x * 32;
    int tx = threadIdx.x & 31, ty = threadIdx.x >> 5;
#pragma unroll
    for (int i = 0; i < 32; i += 8) {
        int k = kb + ty + i;
        t[ty + i][tx] = (k < Kw) ? W[(size_t)k * N + nb + tx] : 0.f;
    }
    __syncthreads();
#pragma unroll
    for (int i = 0; i < 32; i += 8)
        Wtc[(size_t)(nb + ty + i) * KP + kOff + kb + tx] = f2us(t[tx][ty + i]);
}

// single: Wt[n][k] = bf16(W[k][n])
__global__ void k_wt(const float* __restrict__ W, int K, int N,
                     ushort* __restrict__ Wt, int Kp) {
    __shared__ float t[32][33];
    int kb = blockIdx.y * 32, nb = blockIdx.x * 32;
    int tx = threadIdx.x & 31, ty = threadIdx.x >> 5;
#pragma unroll
    for (int i = 0; i < 32; i += 8) {
        int k = kb + ty + i;
        t[ty + i][tx] = (k < K) ? W[(size_t)k * N + nb + tx] : 0.f;
    }
    __syncthreads();
#pragma unroll
    for (int i = 0; i < 32; i += 8)
        Wt[(size_t)(nb + ty + i) * Kp + kb + tx] = f2us(t[tx][ty + i]);
}

// ---------------- MFMA GEMM (m97 structure, two-pass, fused BN partials) ---
// C = A1@B1t^T + A2@B2t^T + bias; A bf16 [M,K] lda, Bt bf16 [N,K] ldb.
// 128x128 tile, BK=32, 256 thr (4 waves), wave = 64x64 quadrant of 4x4 mfma.
// Split-K via blockIdx.z (single-pass callers only): pass-1 pointers advance
// z*K1 in k; Cf advances z*cStrideZ.

#define BK 32

__global__ __launch_bounds__(256)
void k_mgemm(const ushort* __restrict__ A1, int lda1, const ushort* __restrict__ B1t, int ldb1, int K1,
             const ushort* __restrict__ A2, int lda2, const ushort* __restrict__ B2t, int ldb2, int K2,
             const float* __restrict__ bias, float* __restrict__ Cf, ushort* __restrict__ Cbf,
             int ldc, int fuse_lrelu, float* __restrict__ s1p, float* __restrict__ s2p,
             size_t cStrideZ) {
    __shared__ __align__(16) ushort As[128 * BK];
    __shared__ __align__(16) ushort Bs[128 * BK];
    __shared__ float sb1[4][64];
    __shared__ float sb2[4][64];
    const int tid = threadIdx.x;
    const int lane = tid & 63;
    const int w = tid >> 6;
    const int rowBase = blockIdx.y * 128;
    const int colBase = blockIdx.x * 128;
    const int m0 = (w & 1) * 64;
    const int n0 = (w >> 1) * 64;
    const int z = blockIdx.z;
    A1 += (size_t)z * K1;       // k-offset within row (lda spans full K)
    B1t += (size_t)z * K1;
    if (Cf) Cf += (size_t)z * cStrideZ;

    f32x4 acc[4][4];
#pragma unroll
    for (int mi = 0; mi < 4; ++mi)
#pragma unroll
        for (int ni = 0; ni < 4; ++ni) acc[mi][ni] = (f32x4){0.f, 0.f, 0.f, 0.f};

    const int i0 = w * 128 + lane;
    const int i1 = i0 + 64;
    const int r0i = i0 >> 2, c0i = i0 & 3;
    const int r1i = i1 >> 2, c1i = i1 & 3;
    ushort* ldsA0 = As + w * 1024;
    ushort* ldsA1 = As + w * 1024 + 512;
    ushort* ldsB0 = Bs + w * 1024;
    ushort* ldsB1 = Bs + w * 1024 + 512;
    const int la = lane & 15, q = lane >> 4;

    for (int pass = 0; pass < 2; ++pass) {
        const ushort* A  = pass ? A2 : A1;
        const ushort* Bt = pass ? B2t : B1t;
        const int K   = pass ? K2 : K1;
        const int lda = pass ? lda2 : lda1;
        const int ldb = pass ? ldb2 : ldb1;
        if (A == nullptr) continue;
        const ushort* gA0 = A + (size_t)(rowBase + r0i) * lda + c0i * 8;
        const ushort* gA1 = A + (size_t)(rowBase + r1i) * lda + c1i * 8;
        const ushort* gB0 = Bt + (size_t)(colBase + r0i) * ldb + c0i * 8;
        const ushort* gB1 = Bt + (size_t)(colBase + r1i) * ldb + c1i * 8;
        for (int kt = 0; kt < K; kt += BK) {
            gll16(gA0 + kt, ldsA0);
            gll16(gA1 + kt, ldsA1);
            gll16(gB0 + kt, ldsB0);
            gll16(gB1 + kt, ldsB1);
            __syncthreads();
            bf16x8 av[4], bv[4];
#pragma unroll
            for (int mi = 0; mi < 4; ++mi)
                av[mi] = *(const bf16x8*)&As[(m0 + mi * 16 + la) * BK + q * 8];
#pragma unroll
            for (int ni = 0; ni < 4; ++ni)
                bv[ni] = *(const bf16x8*)&Bs[(n0 + ni * 16 + la) * BK + q * 8];
#pragma unroll
            for (int mi = 0; mi < 4; ++mi)
#pragma unroll
                for (int ni = 0; ni < 4; ++ni)
                    acc[mi][ni] = __builtin_amdgcn_mfma_f32_16x16x32_bf16(
                        av[mi], bv[ni], acc[mi][ni], 0, 0, 0);
            __syncthreads();
        }
    }

    // ---- C store (C/D layout: col = lane&15, row = q*4 + reg) ----
#pragma unroll
    for (int mi = 0; mi < 4; ++mi) {
#pragma unroll
        for (int ni = 0; ni < 4; ++ni) {
            const int lc = colBase + n0 + ni * 16 + la;
            const float bv = bias ? bias[lc] : 0.f;
#pragma unroll
            for (int r = 0; r < 4; ++r) {
                const int row = rowBase + m0 + mi * 16 + q * 4 + r;
                float v = acc[mi][ni][r] + bv;
                if (fuse_lrelu) v = v > 0.f ? v : SLOPE * v;
                if (Cbf) Cbf[(size_t)row * ldc + lc] = f2us(v);
                else     Cf[(size_t)row * ldc + lc] = v;
            }
        }
    }

    // ---- fused BN partial stats (pre-activation, fp32 exact) ----
    if (s1p) {
#pragma unroll
        for (int ni = 0; ni < 4; ++ni) {
            const int lc = colBase + n0 + ni * 16 + la;
            const float bv = bias ? bias[lc] : 0.f;
            float t1 = 0.f, t2 = 0.f;
#pragma unroll
            for (int mi = 0; mi < 4; ++mi)
#pragma unroll
                for (int r = 0; r < 4; ++r) {
                    float v = acc[mi][ni][r] + bv;
                    t1 += v;
                    t2 += v * v;
                }
            t1 += __shfl_xor(t1, 16);
            t1 += __shfl_xor(t1, 32);
            t2 += __shfl_xor(t2, 16);
            t2 += __shfl_xor(t2, 32);
            if (q == 0) {
                sb1[w][ni * 16 + la] = t1;
                sb2[w][ni * 16 + la] = t2;
            }
        }
        __syncthreads();
        if (tid < 128) {
            int half = tid >> 6, j = tid & 63;
            float v1 = sb1[2 * half][j] + sb1[2 * half + 1][j];
            float v2 = sb2[2 * half][j] + sb2[2 * half + 1][j];
            size_t o = (size_t)blockIdx.y * ldc + colBase + half * 64 + j;
            s1p[o] = v1;
            s2p[o] = v2;
        }
    }
}

// ---------------- BatchNorm finalize ----------------

__global__ void k_bn_finalize(const float* __restrict__ p1, const float* __restrict__ p2,
                              const float* __restrict__ gamma, const float* __restrict__ beta,
                              float* __restrict__ scale, float* __restrict__ shift) {
    int c = blockIdx.x * 256 + threadIdx.x;
    if (c >= HID) return;
    float s1 = 0.f, s2 = 0.f;
    for (int rb = 0; rb < MR; ++rb) {
        s1 += p1[(size_t)rb * HID + c];
        s2 += p2[(size_t)rb * HID + c];
    }
    float mean = s1 * (1.f / (float)NN);
    float var = s2 * (1.f / (float)NN) - mean * mean;
    var = fmaxf(var, 0.f);
    float sc = gamma[c] * rsqrtf(var + EPS);
    scale[c] = sc;
    shift[c] = beta[c] - mean * sc;
}

// ---------------- fused BN + pooling ----------------

__global__ void k_poolbn(const ushort* __restrict__ Ybf,
                         const float* __restrict__ scale, const float* __restrict__ shift,
                         const int* __restrict__ gstart, ushort* __restrict__ hgbf) {
    int g = blockIdx.y;
    int col = blockIdx.x * 256 + threadIdx.x;
    if (g >= GG) {
        hgbf[(size_t)g * HID + col] = 0;
        return;
    }
    int s = gstart[g], e = gstart[g + 1];
    float sc = scale[col], sh = shift[col];
    float acc = 0.f;
    for (int n = s; n < e; ++n) {
        float v = sc * us2f(Ybf[(size_t)n * HID + col]) + sh;
        acc += v > 0.f ? v : SLOPE * v;
    }
    hgbf[(size_t)g * HID + col] = f2us(acc / fmaxf((float)(e - s), 1.f));
}

__global__ void k_gstart(const int* __restrict__ gid, int* __restrict__ gstart) {
    int g = threadIdx.x;
    if (g > GG) return;
    int lo = 0, hi = NN;
    while (lo < hi) {
        int mid = (lo + hi) >> 1;
        if (gid[mid] < g) lo = mid + 1; else hi = mid;
    }
    gstart[g] = lo;
}

// ---------------- split-K reduce for head GEMMs ----------------

__global__ void k_redhead(const float* __restrict__ part, int P, size_t strideZ,
                          const float* __restrict__ bias, int ldc,
                          ushort* __restrict__ obf, float* __restrict__ of, int n) {
    int i = blockIdx.x * 256 + threadIdx.x;
    if (i >= n) return;
    float s = 0.f;
    for (int p = 0; p < P; ++p) s += part[(size_t)p * strideZ + i];
    s += bias[i % ldc];
    s = s > 0.f ? s : SLOPE * s;
    if (obf) obf[i] = f2us(s);
    else     of[i] = s;
}

__global__ void k_fc3(const float* __restrict__ x2, const float* __restrict__ W,
                      const float* __restrict__ b, float* __restrict__ out) {
    int g = blockIdx.x;
    int tid = threadIdx.x;
    float part[NCLS];
#pragma unroll
    for (int c = 0; c < NCLS; ++c) part[c] = 0.f;
    for (int k = tid; k < MID; k += 256) {
        float x = x2[(size_t)g * MID + k];
        const float* wr = W + (size_t)k * NCLS;
#pragma unroll
        for (int c = 0; c < NCLS; ++c) part[c] += x * wr[c];
    }
    __shared__ float red[4][NCLS];
    int lane = tid & 63, w = tid >> 6;
#pragma unroll
    for (int c = 0; c < NCLS; ++c) {
        float v = part[c];
        for (int o = 32; o > 0; o >>= 1) v += __shfl_down(v, o, 64);
        if (lane == 0) red[w][c] = v;
    }
    __syncthreads();
    if (tid < NCLS)
        out[(size_t)g * NCLS + tid] = red[0][tid] + red[1][tid] + red[2][tid] + red[3][tid] + b[tid];
}

// ---------------- launcher ----------------

extern "C" void kernel_launch(void* const* d_in, const int* in_sizes, int n_in,
                              void* d_out, int out_size, void* d_ws, size_t ws_size,
                              hipStream_t stream) {
    const float* h        = (const float*)d_in[0];
    const int*   src      = (const int*)d_in[1];
    const int*   dst      = (const int*)d_in[2];
    const int*   graph_id = (const int*)d_in[3];
    const float* Ws1 = (const float*)d_in[4];
    const float* Wn1 = (const float*)d_in[5];
    const float* b1  = (const float*)d_in[6];
    const float* Ws2 = (const float*)d_in[7];
    const float* Wn2 = (const float*)d_in[8];
    const float* b2  = (const float*)d_in[9];
    const float* Ws3 = (const float*)d_in[10];
    const float* Wn3 = (const float*)d_in[11];
    const float* b3  = (const float*)d_in[12];
    const float* g1  = (const float*)d_in[13];
    const float* be1 = (const float*)d_in[14];
    const float* g2  = (const float*)d_in[15];
    const float* be2 = (const float*)d_in[16];
    const float* g3  = (const float*)d_in[17];
    const float* be3 = (const float*)d_in[18];
    const float* fc1_w = (const float*)d_in[19];
    const float* fc1_b = (const float*)d_in[20];
    const float* fc2_w = (const float*)d_in[21];
    const float* fc2_b = (const float*)d_in[22];
    const float* fc3_w = (const float*)d_in[23];
    const float* fc3_b = (const float*)d_in[24];
    float* out = (float*)d_out;

    size_t off_b = 0;
    auto alloc = [&](size_t bytes) -> void* {
        void* p = (char*)d_ws + off_b;
        off_b += (bytes + 255) & ~(size_t)255;
        return p;
    };
    ushort* Wt0    = (ushort*)alloc((size_t)2 * HID * HID * 2);  // 16 MiB (2 slots)
    ushort* Wt1    = Wt0 + (size_t)HID * HID;
    ushort* X      = (ushort*)alloc((size_t)NN * HID * 2);       // 64 MiB
    ushort* AggX   = (ushort*)alloc((size_t)NN * HID * 2);       // 64 MiB
    ushort* Ybf    = (ushort*)alloc((size_t)NN * HID * 2);       // 64 MiB
    float*  deg    = (float*)alloc((size_t)NN * 4);
    int*    csroff = (int*)alloc((size_t)(NN + 1) * 4);
    int*    cursor = (int*)alloc((size_t)NN * 4);
    int*    csrsrc = (int*)alloc((size_t)EE * 4);
    float*  p1     = (float*)alloc((size_t)MR * HID * 4);        // 1 MiB
    float*  p2     = (float*)alloc((size_t)MR * HID * 4);        // 1 MiB
    float*  bnsc   = (float*)alloc((size_t)HID * 4);
    float*  bnsh   = (float*)alloc((size_t)HID * 4);
    int*    gstart = (int*)alloc((size_t)(GG + 1) * 4);
    // total ~212 MiB

    // layer-1 concat input [NN,128] in X region (dead before aggbn writes X)
    ushort* Xc128 = X;
    // head scratch in AggX region (dead after layer-3 GEMM; Ybf live till poolbn)
    ushort* hgbf  = AggX;                                     // [128,2048] bf16
    ushort* x1bf  = AggX + (size_t)128 * HID;                 // [128,2048] bf16
    float*  x2f   = (float*)(AggX + (size_t)2 * 128 * HID);   // [128,1024] fp32
    float*  partF = (float*)(AggX + (size_t)3 * 128 * HID);   // 4 MiB fp32 partials

    // ---- CSR build ----
    k_zero_i<<<dim3(NN / 256), dim3(256), 0, stream>>>(cursor, NN);
    k_count<<<dim3(EE / 256), dim3(256), 0, stream>>>(dst, cursor);
    k_scan<<<dim3(1), dim3(1024), 0, stream>>>(cursor, csroff, deg);
    k_zero_i<<<dim3(NN / 256), dim3(256), 0, stream>>>(cursor, NN);
    k_fill<<<dim3(EE / 256), dim3(256), 0, stream>>>(src, dst, csroff, cursor, csrsrc);
    k_gstart<<<dim3(1), dim3(128), 0, stream>>>(graph_id, gstart);

    // ---- layer 1: concat input K=128, single pass ----
    k_h2bf_c<<<dim3(NN * 64 / 256), dim3(256), 0, stream>>>(h, Xc128);
    k_agg_small_c<<<dim3(NN), dim3(64), 0, stream>>>(h, Xc128, csroff, csrsrc, deg);
    k_wt2c<<<dim3(HID / 32, 2, 2), dim3(256), 0, stream>>>(Ws1, Wn1, INF, HID, Wt0, 128);
    k_mgemm<<<dim3(HID / 128, NN / 128, 1), dim3(256), 0, stream>>>(
        Xc128, 128, Wt0, 128, 128,
        (const ushort*)nullptr, 0, (const ushort*)nullptr, 0, 0,
        b1, (float*)nullptr, Ybf, HID, 0, p1, p2, 0);
    k_bn_finalize<<<dim3(HID / 256), dim3(256), 0, stream>>>(p1, p2, g1, be1, bnsc, bnsh);
    k_aggbn<<<dim3(NN), dim3(256), 0, stream>>>(Ybf, bnsc, bnsh, X, AggX, csroff, csrsrc, deg);

    // ---- layer 2: two-pass K=2048+2048 (R6-proven codegen) ----
    k_wt2<<<dim3(HID / 32, HID / 32, 2), dim3(256), 0, stream>>>(Ws2, Wn2, HID, HID, Wt0, Wt1, HID);
    k_mgemm<<<dim3(HID / 128, NN / 128, 1), dim3(256), 0, stream>>>(
        X, HID, Wt0, HID, HID,
        AggX, HID, Wt1, HID, HID,
        b2, (float*)nullptr, Ybf, HID, 0, p1, p2, 0);
    k_bn_finalize<<<dim3(HID / 256), dim3(256), 0, stream>>>(p1, p2, g2, be2, bnsc, bnsh);
    k_aggbn<<<dim3(NN), dim3(256), 0, stream>>>(Ybf, bnsc, bnsh, X, AggX, csroff, csrsrc, deg);

    // ---- layer 3 ----
    k_wt2<<<dim3(HID / 32, HID / 32, 2), dim3(256), 0, stream>>>(Ws3, Wn3, HID, HID, Wt0, Wt1, HID);
    k_mgemm<<<dim3(HID / 128, NN / 128, 1), dim3(256), 0, stream>>>(
        X, HID, Wt0, HID, HID,
        AggX, HID, Wt1, HID, HID,
        b3, (float*)nullptr, Ybf, HID, 0, p1, p2, 0);
    k_bn_finalize<<<dim3(HID / 256), dim3(256), 0, stream>>>(p1, p2, g3, be3, bnsc, bnsh);

    // ---- fused BN + pooling (Ybf -> padded bf16 hg; AggX region now scratch) ----
    k_poolbn<<<dim3(HID / 256, 128), dim3(256), 0, stream>>>(Ybf, bnsc, bnsh, gstart, hgbf);

    // ---- MLP head (split-K x4, deterministic two-stage) ----
    k_wt<<<dim3(HID / 32, HID / 32), dim3(256), 0, stream>>>(fc1_w, HID, HID, Wt0, HID);
    k_wt<<<dim3(MID / 32, HID / 32), dim3(256), 0, stream>>>(fc2_w, HID, MID, Wt1, HID);
    k_mgemm<<<dim3(HID / 128, 1, 4), dim3(256), 0, stream>>>(
        hgbf, HID, Wt0, HID, HID / 4,
        (const ushort*)nullptr, 0, (const ushort*)nullptr, 0, 0,
        (const float*)nullptr, partF, (ushort*)nullptr, HID, 0,
        (float*)nullptr, (float*)nullptr, (size_t)128 * HID);
    k_redhead<<<dim3(128 * HID / 256), dim3(256), 0, stream>>>(
        partF, 4, (size_t)128 * HID, fc1_b, HID, x1bf, (float*)nullptr, 128 * HID);
    k_mgemm<<<dim3(MID / 128, 1, 4), dim3(256), 0, stream>>>(
        x1bf, HID, Wt1, HID, HID / 4,
        (const ushort*)nullptr, 0, (const ushort*)nullptr, 0, 0,
        (const float*)nullptr, partF, (ushort*)nullptr, MID, 0,
        (float*)nullptr, (float*)nullptr, (size_t)128 * MID);
    k_redhead<<<dim3(128 * MID / 256), dim3(256), 0, stream>>>(
        partF, 4, (size_t)128 * MID, fc2_b, MID, (ushort*)nullptr, x2f, 128 * MID);
    k_fc3<<<dim3(GG), dim3(256), 0, stream>>>(x2f, fc3_w, fc3_b, out);
}

// Round 9
// 1078.824 us; speedup vs baseline: 1.7186x; 1.1614x over previous
//
#include <hip/hip_runtime.h>
#include <hip/hip_bf16.h>

#define NN   16384
#define EE   65536
#define GG   64
#define INF  63
#define HID  2048
#define MID  1024
#define NCLS 18
#define EPS  1e-5f
#define SLOPE 0.01f
#define MR   (NN / 128)   // 128 block-rows for BN partials

typedef unsigned short ushort;
typedef unsigned int uint;

using bf16x8 = __attribute__((ext_vector_type(8))) __bf16;
using f32x4  = __attribute__((ext_vector_type(4))) float;

__device__ __forceinline__ ushort f2us(float x) {
    __hip_bfloat16 b = __float2bfloat16(x);
    return __builtin_bit_cast(ushort, b);
}
__device__ __forceinline__ float us2f(ushort u) {
    return __bfloat162float(__builtin_bit_cast(__hip_bfloat16, u));
}

// async global->LDS, 16B per lane; LDS base wave-uniform, HW adds lane*16
__device__ __forceinline__ void gll16(const ushort* g, ushort* l) {
    __builtin_amdgcn_global_load_lds(
        (const __attribute__((address_space(1))) uint*)g,
        (__attribute__((address_space(3))) uint*)l, 16, 0, 0);
}

// ---------------- utility ----------------

__global__ void k_zero_i(int* __restrict__ p, int n) {
    int i = blockIdx.x * blockDim.x + threadIdx.x;
    if (i < n) p[i] = 0;
}

// ---------------- CSR build (by dst) ----------------

__global__ void k_count(const int* __restrict__ dst, int* __restrict__ cnt) {
    int e = blockIdx.x * blockDim.x + threadIdx.x;
    if (e < EE) atomicAdd(&cnt[dst[e]], 1);
}

__global__ void k_scan(const int* __restrict__ cnt, int* __restrict__ off,
                       float* __restrict__ deg) {
    __shared__ int sh[1024];
    int t = threadIdx.x;
    int base = t * 16;
    int loc[16];
    int s = 0;
#pragma unroll
    for (int i = 0; i < 16; ++i) {
        int c = cnt[base + i];
        loc[i] = s;
        s += c;
        deg[base + i] = (float)c;
    }
    sh[t] = s;
    __syncthreads();
    for (int d = 1; d < 1024; d <<= 1) {
        int v = (t >= d) ? sh[t - d] : 0;
        __syncthreads();
        sh[t] += v;
        __syncthreads();
    }
    int excl = sh[t] - s;
#pragma unroll
    for (int i = 0; i < 16; ++i) off[base + i] = excl + loc[i];
    if (t == 1023) off[NN] = sh[1023];
}

__global__ void k_fill(const int* __restrict__ src, const int* __restrict__ dst,
                       const int* __restrict__ off, int* __restrict__ cur,
                       int* __restrict__ csr_src) {
    int e = blockIdx.x * blockDim.x + threadIdx.x;
    if (e < EE) {
        int d = dst[e];
        int p = atomicAdd(&cur[d], 1);
        csr_src[off[d] + p] = src[e];
    }
}

// ---------------- layer-1 prep (into concat [NN,128]) ----------------

__global__ void k_h2bf_c(const float* __restrict__ h, ushort* __restrict__ Xc) {
    int i = blockIdx.x * 256 + threadIdx.x;  // over NN*64
    int r = i >> 6, c = i & 63;
    Xc[(size_t)r * 128 + c] = (c < INF) ? f2us(h[(size_t)r * INF + c]) : (ushort)0;
}

__global__ void k_agg_small_c(const float* __restrict__ X, ushort* __restrict__ Xc,
                              const int* __restrict__ off, const int* __restrict__ csr_src,
                              const float* __restrict__ deg) {
    int v = blockIdx.x;
    int f = threadIdx.x;  // 64
    float acc = 0.f;
    if (f < INF) {
        int s = off[v], e = off[v + 1];
        for (int i = s; i < e; ++i) acc += X[(size_t)csr_src[i] * INF + f];
        acc /= fmaxf(deg[v], 1.f);
    }
    Xc[(size_t)v * 128 + 64 + f] = f2us(acc);
}

// ---------------- fused BN-apply + aggregation ----------------
// X[v]    = bf16(lrelu(sc*Ybf[v]+sh))
// AggX[v] = bf16(mean_nb lrelu(sc*Ybf[u]+sh))  (fp32 accum)

__global__ void k_aggbn(const ushort* __restrict__ Ybf,
                        const float* __restrict__ sc8, const float* __restrict__ sh8,
                        ushort* __restrict__ X, ushort* __restrict__ AggX,
                        const int* __restrict__ off, const int* __restrict__ csr_src,
                        const float* __restrict__ deg) {
    int v = blockIdx.x;
    int t = threadIdx.x;
    int c = t * 8;
    float sc[8], sh[8];
    *(float4*)&sc[0] = *(const float4*)&sc8[c];
    *(float4*)&sc[4] = *(const float4*)&sc8[c + 4];
    *(float4*)&sh[0] = *(const float4*)&sh8[c];
    *(float4*)&sh[4] = *(const float4*)&sh8[c + 4];

    // own row
    {
        uint4 u = ((const uint4*)(Ybf + (size_t)v * HID))[t];
        uint wds[4] = {u.x, u.y, u.z, u.w};
        uint o[4];
#pragma unroll
        for (int j = 0; j < 4; ++j) {
            float a = sc[2 * j] * us2f((ushort)(wds[j] & 0xffffu)) + sh[2 * j];
            float b = sc[2 * j + 1] * us2f((ushort)(wds[j] >> 16)) + sh[2 * j + 1];
            a = a > 0.f ? a : SLOPE * a;
            b = b > 0.f ? b : SLOPE * b;
            o[j] = (uint)f2us(a) | ((uint)f2us(b) << 16);
        }
        ((uint4*)(X + (size_t)v * HID))[t] = make_uint4(o[0], o[1], o[2], o[3]);
    }

    // neighbor mean
    int s = off[v], e = off[v + 1];
    float acc[8];
#pragma unroll
    for (int j = 0; j < 8; ++j) acc[j] = 0.f;
    for (int i = s; i < e; ++i) {
        uint4 u = ((const uint4*)(Ybf + (size_t)csr_src[i] * HID))[t];
        uint wds[4] = {u.x, u.y, u.z, u.w};
#pragma unroll
        for (int j = 0; j < 4; ++j) {
            float a = sc[2 * j] * us2f((ushort)(wds[j] & 0xffffu)) + sh[2 * j];
            float b = sc[2 * j + 1] * us2f((ushort)(wds[j] >> 16)) + sh[2 * j + 1];
            acc[2 * j]     += a > 0.f ? a : SLOPE * a;
            acc[2 * j + 1] += b > 0.f ? b : SLOPE * b;
        }
    }
    float inv = 1.f / fmaxf(deg[v], 1.f);
    uint o[4];
#pragma unroll
    for (int j = 0; j < 4; ++j)
        o[j] = (uint)f2us(acc[2 * j] * inv) | ((uint)f2us(acc[2 * j + 1] * inv) << 16);
    ((uint4*)(AggX + (size_t)v * HID))[t] = make_uint4(o[0], o[1], o[2], o[3]);
}

// ---------------- weight transposes ----------------

// paired: z=0: W0 -> Wt0 ; z=1: W1 -> Wt1.  Wt[n][k] = bf16(W[k][n]), pad 0.
__global__ void k_wt2(const float* __restrict__ W0, const float* __restrict__ W1,
                      int K, int N, ushort* __restrict__ Wt0, ushort* __restrict__ Wt1,
                      int Kp) {
    const float* W = blockIdx.z ? W1 : W0;
    ushort* Wt = blockIdx.z ? Wt1 : Wt0;
    __shared__ float t[32][33];
    int kb = blockIdx.y * 32, nb = blockIdx.x * 32;
    int tx = threadIdx.x & 31, ty = threadIdx.x >> 5;
#pragma unroll
    for (int i = 0; i < 32; i += 8) {
        int k = kb + ty + i;
        t[ty + i][tx] = (k < K) ? W[(size_t)k * N + nb + tx] : 0.f;
    }
    __syncthreads();
#pragma unroll
    for (int i = 0; i < 32; i += 8)
        Wt[(size_t)(nb + ty + i) * Kp + kb + tx] = f2us(t[tx][ty + i]);
}

// concat pair into one [N,KP] buffer: z=0 -> k-cols [0,KP/2), z=1 -> [KP/2,KP)
__global__ void k_wt2c(const float* __restrict__ W0, const float* __restrict__ W1,
                       int Kw, int N, ushort* __restrict__ Wtc, int KP) {
    const float* W = blockIdx.z ? W1 : W0;
    const int kOff = blockIdx.z ? (KP / 2) : 0;
    __shared__ float t[32][33];
    int kb = blockIdx.y * 32, nb = blockIdx.x * 32;
    int tx = threadIdx.x & 31, ty = threadIdx.x >> 5;
#pragma unroll
    for (int i = 0; i < 32; i += 8) {
        int k = kb + ty + i;
        t[ty + i][tx] = (k < Kw) ? W[(size_t)k * N + nb + tx] : 0.f;
    }
    __syncthreads();
#pragma unroll
    for (int i = 0; i < 32; i += 8)
        Wtc[(size_t)(nb + ty + i) * KP + kOff + kb + tx] = f2us(t[tx][ty + i]);
}

// single: Wt[n][k] = bf16(W[k][n])
__global__ void k_wt(const float* __restrict__ W, int K, int N,
                     ushort* __restrict__ Wt, int Kp) {
    __shared__ float t[32][33];
    int kb = blockIdx.y * 32, nb = blockIdx.x * 32;
    int tx = threadIdx.x & 31, ty = threadIdx.x >> 5;
#pragma unroll
    for (int i = 0; i < 32; i += 8) {
        int k = kb + ty + i;
        t[ty + i][tx] = (k < K) ? W[(size_t)k * N + nb + tx] : 0.f;
    }
    __syncthreads();
#pragma unroll
    for (int i = 0; i < 32; i += 8)
        Wt[(size_t)(nb + ty + i) * Kp + kb + tx] = f2us(t[tx][ty + i]);
}

// ---------------- MFMA GEMM (two-pass, BK=64, XOR-swizzled LDS) ------------
// C = A1@B1t^T + A2@B2t^T + bias; A bf16 [M,K] lda, Bt bf16 [N,K] ldb.
// 128x128 tile, BK=64 (32 MFMA per barrier), 256 thr (4 waves),
// wave = 64x64 quadrant of 4x4 mfma 16x16x32.
// LDS layout: [row][64] k-contiguous, but chunk c8 (8 elems) of row r holds
// GLOBAL k-chunk (c8 ^ (r&7)) -> reader uses ((kk*4+q) ^ (la&7)) -> 2-way
// bank aliasing only (free). Staging permutes global addresses per lane,
// still within the same 128B row segment (coalesced).
// Split-K via blockIdx.z (single-pass callers only): pass-1 pointers advance
// z*K1 in k; Cf advances z*cStrideZ. K must be a multiple of 64.

#define BK 64

__global__ __launch_bounds__(256)
void k_mgemm(const ushort* __restrict__ A1, int lda1, const ushort* __restrict__ B1t, int ldb1, int K1,
             const ushort* __restrict__ A2, int lda2, const ushort* __restrict__ B2t, int ldb2, int K2,
             const float* __restrict__ bias, float* __restrict__ Cf, ushort* __restrict__ Cbf,
             int ldc, int fuse_lrelu, float* __restrict__ s1p, float* __restrict__ s2p,
             size_t cStrideZ) {
    __shared__ __align__(16) ushort As[128 * BK];
    __shared__ __align__(16) ushort Bs[128 * BK];
    __shared__ float sb1[4][64];
    __shared__ float sb2[4][64];
    const int tid = threadIdx.x;
    const int lane = tid & 63;
    const int w = tid >> 6;
    const int rowBase = blockIdx.y * 128;
    const int colBase = blockIdx.x * 128;
    const int m0 = (w & 1) * 64;
    const int n0 = (w >> 1) * 64;
    const int z = blockIdx.z;
    A1 += (size_t)z * K1;       // k-offset within row (lda spans full K)
    B1t += (size_t)z * K1;
    if (Cf) Cf += (size_t)z * cStrideZ;

    f32x4 acc[4][4];
#pragma unroll
    for (int mi = 0; mi < 4; ++mi)
#pragma unroll
        for (int ni = 0; ni < 4; ++ni) acc[mi][ni] = (f32x4){0.f, 0.f, 0.f, 0.f};

    // staging: 1024 chunks (16B) per matrix = 128 rows x 8 chunks.
    // thread (w,lane) does chunks j*256 + w*64 + lane, j=0..3:
    //   row = j*32 + w*8 + (lane>>3), lds c8 = lane&7,
    //   global k-chunk = (lane&7) ^ (lane>>3)   [= c8 ^ (row&7)]
    const int lrow = w * 8 + (lane >> 3);
    const int gc8 = ((lane & 7) ^ (lane >> 3)) * 8;   // element offset
    const int la = lane & 15, q = lane >> 4;
    const int la7 = lane & 7;

    for (int pass = 0; pass < 2; ++pass) {
        const ushort* A  = pass ? A2 : A1;
        const ushort* Bt = pass ? B2t : B1t;
        const int K   = pass ? K2 : K1;
        const int lda = pass ? lda2 : lda1;
        const int ldb = pass ? ldb2 : ldb1;
        if (A == nullptr) continue;
        const ushort* gA = A + (size_t)(rowBase + lrow) * lda + gc8;
        const ushort* gB = Bt + (size_t)(colBase + lrow) * ldb + gc8;
        for (int kt = 0; kt < K; kt += BK) {
#pragma unroll
            for (int j = 0; j < 4; ++j) {
                gll16(gA + (size_t)(j * 32) * lda + kt, As + j * 2048 + w * 512);
                gll16(gB + (size_t)(j * 32) * ldb + kt, Bs + j * 2048 + w * 512);
            }
            __syncthreads();
#pragma unroll
            for (int kk = 0; kk < 2; ++kk) {
                const int lc8 = ((kk * 4 + q) ^ la7) * 8;
                bf16x8 av[4], bv[4];
#pragma unroll
                for (int mi = 0; mi < 4; ++mi)
                    av[mi] = *(const bf16x8*)&As[(m0 + mi * 16 + la) * BK + lc8];
#pragma unroll
                for (int ni = 0; ni < 4; ++ni)
                    bv[ni] = *(const bf16x8*)&Bs[(n0 + ni * 16 + la) * BK + lc8];
#pragma unroll
                for (int mi = 0; mi < 4; ++mi)
#pragma unroll
                    for (int ni = 0; ni < 4; ++ni)
                        acc[mi][ni] = __builtin_amdgcn_mfma_f32_16x16x32_bf16(
                            av[mi], bv[ni], acc[mi][ni], 0, 0, 0);
            }
            __syncthreads();
        }
    }

    // ---- C store (C/D layout: col = lane&15, row = q*4 + reg) ----
#pragma unroll
    for (int mi = 0; mi < 4; ++mi) {
#pragma unroll
        for (int ni = 0; ni < 4; ++ni) {
            const int lc = colBase + n0 + ni * 16 + la;
            const float bv = bias ? bias[lc] : 0.f;
#pragma unroll
            for (int r = 0; r < 4; ++r) {
                const int row = rowBase + m0 + mi * 16 + q * 4 + r;
                float v = acc[mi][ni][r] + bv;
                if (fuse_lrelu) v = v > 0.f ? v : SLOPE * v;
                if (Cbf) Cbf[(size_t)row * ldc + lc] = f2us(v);
                else     Cf[(size_t)row * ldc + lc] = v;
            }
        }
    }

    // ---- fused BN partial stats (pre-activation, fp32 exact) ----
    if (s1p) {
#pragma unroll
        for (int ni = 0; ni < 4; ++ni) {
            const int lc = colBase + n0 + ni * 16 + la;
            const float bv = bias ? bias[lc] : 0.f;
            float t1 = 0.f, t2 = 0.f;
#pragma unroll
            for (int mi = 0; mi < 4; ++mi)
#pragma unroll
                for (int r = 0; r < 4; ++r) {
                    float v = acc[mi][ni][r] + bv;
                    t1 += v;
                    t2 += v * v;
                }
            t1 += __shfl_xor(t1, 16);
            t1 += __shfl_xor(t1, 32);
            t2 += __shfl_xor(t2, 16);
            t2 += __shfl_xor(t2, 32);
            if (q == 0) {
                sb1[w][ni * 16 + la] = t1;
                sb2[w][ni * 16 + la] = t2;
            }
        }
        __syncthreads();
        if (tid < 128) {
            int half = tid >> 6, j = tid & 63;
            float v1 = sb1[2 * half][j] + sb1[2 * half + 1][j];
            float v2 = sb2[2 * half][j] + sb2[2 * half + 1][j];
            size_t o = (size_t)blockIdx.y * ldc + colBase + half * 64 + j;
            s1p[o] = v1;
            s2p[o] = v2;
        }
    }
}

// ---------------- BatchNorm finalize ----------------

__global__ void k_bn_finalize(const float* __restrict__ p1, const float* __restrict__ p2,
                              const float* __restrict__ gamma, const float* __restrict__ beta,
                              float* __restrict__ scale, float* __restrict__ shift) {
    int c = blockIdx.x * 256 + threadIdx.x;
    if (c >= HID) return;
    float s1 = 0.f, s2 = 0.f;
    for (int rb = 0; rb < MR; ++rb) {
        s1 += p1[(size_t)rb * HID + c];
        s2 += p2[(size_t)rb * HID + c];
    }
    float mean = s1 * (1.f / (float)NN);
    float var = s2 * (1.f / (float)NN) - mean * mean;
    var = fmaxf(var, 0.f);
    float sc = gamma[c] * rsqrtf(var + EPS);
    scale[c] = sc;
    shift[c] = beta[c] - mean * sc;
}

// ---------------- fused BN + pooling ----------------

__global__ void k_poolbn(const ushort* __restrict__ Ybf,
                         const float* __restrict__ scale, const float* __restrict__ shift,
                         const int* __restrict__ gstart, ushort* __restrict__ hgbf) {
    int g = blockIdx.y;
    int col = blockIdx.x * 256 + threadIdx.x;
    if (g >= GG) {
        hgbf[(size_t)g * HID + col] = 0;
        return;
    }
    int s = gstart[g], e = gstart[g + 1];
    float sc = scale[col], sh = shift[col];
    float acc = 0.f;
    for (int n = s; n < e; ++n) {
        float v = sc * us2f(Ybf[(size_t)n * HID + col]) + sh;
        acc += v > 0.f ? v : SLOPE * v;
    }
    hgbf[(size_t)g * HID + col] = f2us(acc / fmaxf((float)(e - s), 1.f));
}

__global__ void k_gstart(const int* __restrict__ gid, int* __restrict__ gstart) {
    int g = threadIdx.x;
    if (g > GG) return;
    int lo = 0, hi = NN;
    while (lo < hi) {
        int mid = (lo + hi) >> 1;
        if (gid[mid] < g) lo = mid + 1; else hi = mid;
    }
    gstart[g] = lo;
}

// ---------------- split-K reduce for head GEMMs ----------------

__global__ void k_redhead(const float* __restrict__ part, int P, size_t strideZ,
                          const float* __restrict__ bias, int ldc,
                          ushort* __restrict__ obf, float* __restrict__ of, int n) {
    int i = blockIdx.x * 256 + threadIdx.x;
    if (i >= n) return;
    float s = 0.f;
    for (int p = 0; p < P; ++p) s += part[(size_t)p * strideZ + i];
    s += bias[i % ldc];
    s = s > 0.f ? s : SLOPE * s;
    if (obf) obf[i] = f2us(s);
    else     of[i] = s;
}

__global__ void k_fc3(const float* __restrict__ x2, const float* __restrict__ W,
                      const float* __restrict__ b, float* __restrict__ out) {
    int g = blockIdx.x;
    int tid = threadIdx.x;
    float part[NCLS];
#pragma unroll
    for (int c = 0; c < NCLS; ++c) part[c] = 0.f;
    for (int k = tid; k < MID; k += 256) {
        float x = x2[(size_t)g * MID + k];
        const float* wr = W + (size_t)k * NCLS;
#pragma unroll
        for (int c = 0; c < NCLS; ++c) part[c] += x * wr[c];
    }
    __shared__ float red[4][NCLS];
    int lane = tid & 63, w = tid >> 6;
#pragma unroll
    for (int c = 0; c < NCLS; ++c) {
        float v = part[c];
        for (int o = 32; o > 0; o >>= 1) v += __shfl_down(v, o, 64);
        if (lane == 0) red[w][c] = v;
    }
    __syncthreads();
    if (tid < NCLS)
        out[(size_t)g * NCLS + tid] = red[0][tid] + red[1][tid] + red[2][tid] + red[3][tid] + b[tid];
}

// ---------------- launcher ----------------

extern "C" void kernel_launch(void* const* d_in, const int* in_sizes, int n_in,
                              void* d_out, int out_size, void* d_ws, size_t ws_size,
                              hipStream_t stream) {
    const float* h        = (const float*)d_in[0];
    const int*   src      = (const int*)d_in[1];
    const int*   dst      = (const int*)d_in[2];
    const int*   graph_id = (const int*)d_in[3];
    const float* Ws1 = (const float*)d_in[4];
    const float* Wn1 = (const float*)d_in[5];
    const float* b1  = (const float*)d_in[6];
    const float* Ws2 = (const float*)d_in[7];
    const float* Wn2 = (const float*)d_in[8];
    const float* b2  = (const float*)d_in[9];
    const float* Ws3 = (const float*)d_in[10];
    const float* Wn3 = (const float*)d_in[11];
    const float* b3  = (const float*)d_in[12];
    const float* g1  = (const float*)d_in[13];
    const float* be1 = (const float*)d_in[14];
    const float* g2  = (const float*)d_in[15];
    const float* be2 = (const float*)d_in[16];
    const float* g3  = (const float*)d_in[17];
    const float* be3 = (const float*)d_in[18];
    const float* fc1_w = (const float*)d_in[19];
    const float* fc1_b = (const float*)d_in[20];
    const float* fc2_w = (const float*)d_in[21];
    const float* fc2_b = (const float*)d_in[22];
    const float* fc3_w = (const float*)d_in[23];
    const float* fc3_b = (const float*)d_in[24];
    float* out = (float*)d_out;

    size_t off_b = 0;
    auto alloc = [&](size_t bytes) -> void* {
        void* p = (char*)d_ws + off_b;
        off_b += (bytes + 255) & ~(size_t)255;
        return p;
    };
    ushort* Wt0    = (ushort*)alloc((size_t)2 * HID * HID * 2);  // 16 MiB (2 slots)
    ushort* Wt1    = Wt0 + (size_t)HID * HID;
    ushort* X      = (ushort*)alloc((size_t)NN * HID * 2);       // 64 MiB
    ushort* AggX   = (ushort*)alloc((size_t)NN * HID * 2);       // 64 MiB
    ushort* Ybf    = (ushort*)alloc((size_t)NN * HID * 2);       // 64 MiB
    float*  deg    = (float*)alloc((size_t)NN * 4);
    int*    csroff = (int*)alloc((size_t)(NN + 1) * 4);
    int*    cursor = (int*)alloc((size_t)NN * 4);
    int*    csrsrc = (int*)alloc((size_t)EE * 4);
    float*  p1     = (float*)alloc((size_t)MR * HID * 4);        // 1 MiB
    float*  p2     = (float*)alloc((size_t)MR * HID * 4);        // 1 MiB
    float*  bnsc   = (float*)alloc((size_t)HID * 4);
    float*  bnsh   = (float*)alloc((size_t)HID * 4);
    int*    gstart = (int*)alloc((size_t)(GG + 1) * 4);
    // total ~212 MiB

    // layer-1 concat input [NN,128] in X region (dead before aggbn writes X)
    ushort* Xc128 = X;
    // head scratch in AggX region (dead after layer-3 GEMM; Ybf live till poolbn)
    ushort* hgbf  = AggX;                                     // [128,2048] bf16
    ushort* x1bf  = AggX + (size_t)128 * HID;                 // [128,2048] bf16
    float*  x2f   = (float*)(AggX + (size_t)2 * 128 * HID);   // [128,1024] fp32
    float*  partF = (float*)(AggX + (size_t)3 * 128 * HID);   // 4 MiB fp32 partials

    // ---- CSR build ----
    k_zero_i<<<dim3(NN / 256), dim3(256), 0, stream>>>(cursor, NN);
    k_count<<<dim3(EE / 256), dim3(256), 0, stream>>>(dst, cursor);
    k_scan<<<dim3(1), dim3(1024), 0, stream>>>(cursor, csroff, deg);
    k_zero_i<<<dim3(NN / 256), dim3(256), 0, stream>>>(cursor, NN);
    k_fill<<<dim3(EE / 256), dim3(256), 0, stream>>>(src, dst, csroff, cursor, csrsrc);
    k_gstart<<<dim3(1), dim3(128), 0, stream>>>(graph_id, gstart);

    // ---- layer 1: concat input K=128, single pass ----
    k_h2bf_c<<<dim3(NN * 64 / 256), dim3(256), 0, stream>>>(h, Xc128);
    k_agg_small_c<<<dim3(NN), dim3(64), 0, stream>>>(h, Xc128, csroff, csrsrc, deg);
    k_wt2c<<<dim3(HID / 32, 2, 2), dim3(256), 0, stream>>>(Ws1, Wn1, INF, HID, Wt0, 128);
    k_mgemm<<<dim3(HID / 128, NN / 128, 1), dim3(256), 0, stream>>>(
        Xc128, 128, Wt0, 128, 128,
        (const ushort*)nullptr, 0, (const ushort*)nullptr, 0, 0,
        b1, (float*)nullptr, Ybf, HID, 0, p1, p2, 0);
    k_bn_finalize<<<dim3(HID / 256), dim3(256), 0, stream>>>(p1, p2, g1, be1, bnsc, bnsh);
    k_aggbn<<<dim3(NN), dim3(256), 0, stream>>>(Ybf, bnsc, bnsh, X, AggX, csroff, csrsrc, deg);

    // ---- layer 2: two-pass K=2048+2048 ----
    k_wt2<<<dim3(HID / 32, HID / 32, 2), dim3(256), 0, stream>>>(Ws2, Wn2, HID, HID, Wt0, Wt1, HID);
    k_mgemm<<<dim3(HID / 128, NN / 128, 1), dim3(256), 0, stream>>>(
        X, HID, Wt0, HID, HID,
        AggX, HID, Wt1, HID, HID,
        b2, (float*)nullptr, Ybf, HID, 0, p1, p2, 0);
    k_bn_finalize<<<dim3(HID / 256), dim3(256), 0, stream>>>(p1, p2, g2, be2, bnsc, bnsh);
    k_aggbn<<<dim3(NN), dim3(256), 0, stream>>>(Ybf, bnsc, bnsh, X, AggX, csroff, csrsrc, deg);

    // ---- layer 3 ----
    k_wt2<<<dim3(HID / 32, HID / 32, 2), dim3(256), 0, stream>>>(Ws3, Wn3, HID, HID, Wt0, Wt1, HID);
    k_mgemm<<<dim3(HID / 128, NN / 128, 1), dim3(256), 0, stream>>>(
        X, HID, Wt0, HID, HID,
        AggX, HID, Wt1, HID, HID,
        b3, (float*)nullptr, Ybf, HID, 0, p1, p2, 0);
    k_bn_finalize<<<dim3(HID / 256), dim3(256), 0, stream>>>(p1, p2, g3, be3, bnsc, bnsh);

    // ---- fused BN + pooling (Ybf -> padded bf16 hg; AggX region now scratch) ----
    k_poolbn<<<dim3(HID / 256, 128), dim3(256), 0, stream>>>(Ybf, bnsc, bnsh, gstart, hgbf);

    // ---- MLP head (split-K x4, deterministic two-stage) ----
    k_wt<<<dim3(HID / 32, HID / 32), dim3(256), 0, stream>>>(fc1_w, HID, HID, Wt0, HID);
    k_wt<<<dim3(MID / 32, HID / 32), dim3(256), 0, stream>>>(fc2_w, HID, MID, Wt1, HID);
    k_mgemm<<<dim3(HID / 128, 1, 4), dim3(256), 0, stream>>>(
        hgbf, HID, Wt0, HID, HID / 4,
        (const ushort*)nullptr, 0, (const ushort*)nullptr, 0, 0,
        (const float*)nullptr, partF, (ushort*)nullptr, HID, 0,
        (float*)nullptr, (float*)nullptr, (size_t)128 * HID);
    k_redhead<<<dim3(128 * HID / 256), dim3(256), 0, stream>>>(
        partF, 4, (size_t)128 * HID, fc1_b, HID, x1bf, (float*)nullptr, 128 * HID);
    k_mgemm<<<dim3(MID / 128, 1, 4), dim3(256), 0, stream>>>(
        x1bf, HID, Wt1, HID, HID / 4,
        (const ushort*)nullptr, 0, (const ushort*)nullptr, 0, 0,
        (const float*)nullptr, partF, (ushort*)nullptr, MID, 0,
        (float*)nullptr, (float*)nullptr, (size_t)128 * MID);
    k_redhead<<<dim3(128 * MID / 256), dim3(256), 0, stream>>>(
        partF, 4, (size_t)128 * MID, fc2_b, MID, (ushort*)nullptr, x2f, 128 * MID);
    k_fc3<<<dim3(GG), dim3(256), 0, stream>>>(x2f, fc3_w, fc3_b, out);
}